// Round 3
// baseline (613.867 us; speedup 1.0000x reference)
//
#include <hip/hip_runtime.h>
#include <hip/hip_bf16.h>
#include <math.h>

#define B_SZ 2
#define L_SZ 2048
#define DMODEL 1024
#define DINNER 2048
#define DSTATE 16
#define DTRANK 64
#define M_ROWS (B_SZ * L_SZ)   // 4096

#define CH 32
#define CLEN (L_SZ / CH)
#define CPB 64

#define KSPLIT 8
#define KC (DINNER / KSPLIT)   // 256

typedef short shortx8 __attribute__((ext_vector_type(8)));
typedef float floatx4 __attribute__((ext_vector_type(4)));
typedef float floatx16 __attribute__((ext_vector_type(16)));

__device__ __forceinline__ float softplusf(float x) {
    return fmaxf(x, 0.f) + log1pf(expf(-fabsf(x)));
}
__device__ __forceinline__ float siluf(float x) {
    return x * (1.f / (1.f + expf(-x)));
}

__device__ __forceinline__ void async_ld16(const void* g, void* l) {
    __builtin_amdgcn_global_load_lds(
        (__attribute__((address_space(1))) void*)(unsigned long long)g,
        (__attribute__((address_space(3))) void*)(unsigned int)(unsigned long long)l,
        16, 0, 0);
}

// ---------------------------------------------------------------------------
// R12 (= R11 resubmitted after infra failure, source unchanged):
// in_proj as K-augmented bf16 GEMM (K'=3072) on the m201 8-phase 256^2
// template. 512 thr / 8 waves (2Mx4N), per-wave 128x64, mfma 16x16x32.
// LDS 128KB = 2 slots x {A,B} x 2 k-halves (each 16KB = 4 k8-groups x 256
// rows x 16B, k8-major => ds_read_b128 2-way-free, no swizzle needed).
// Panelized global layout written by split3 in exact LDS-image order =>
// linear coalesced global_load_lds staging (m104-safe).
// Phase = {ds_reads | stage 1 region | bar | lgkmcnt(0) | setprio(1) |
// 16 MFMA | setprio(0) | [vmcnt(8) at odd phases] | bar}. Counted vmcnt
// NEVER drains to 0 in the main loop (T3+T4); stages are region-safe
// (target freed one phase before issue); issue order == consume order so
// vmcnt(8) exactly drains the 2 regions the next phase-pair reads.
// ---------------------------------------------------------------------------

// fp32 -> 3-segment panelized bf16 in LDS-image order.
// LO==1 (A/activations): segs [h, l, h];  LO==2 (B/weights): segs [h, h, l]
// => sum over K' = xh*wh + xl*wh + xh*wl  (same split-fp32 triple as R8).
// dst short offset = (p*96 + T*2 + s)*8192 + (k8l*256 + rr)*8 + j
//   p=row>>8, rr=row&255; T = seg*16 + (k8s>>3); s=(k8s>>2)&1; k8l=k8s&3
template <int LO>
__global__ __launch_bounds__(256) void split3_kernel(
    const float* __restrict__ src, unsigned short* __restrict__ dst)
{
    int i = blockIdx.x * 256 + threadIdx.x;   // 4096 rows x 128 k8-groups
    int row = i & 4095;
    int k8s = i >> 12;                        // 0..127
    const float* s = src + (size_t)row * 1024 + k8s * 8;
    float4 v0 = *(const float4*)s;
    float4 v1 = *(const float4*)(s + 4);
    float vs[8] = {v0.x, v0.y, v0.z, v0.w, v1.x, v1.y, v1.z, v1.w};
    unsigned short hsv[8], lsv[8];
#pragma unroll
    for (int j = 0; j < 8; ++j) {
        __hip_bfloat16 h = __float2bfloat16(vs[j]);
        __hip_bfloat16 l = __float2bfloat16(vs[j] - __bfloat162float(h));
        hsv[j] = *(unsigned short*)&h;
        lsv[j] = *(unsigned short*)&l;
    }
    shortx8 hv = *(shortx8*)hsv;
    shortx8 lv = *(shortx8*)lsv;
    int p = row >> 8, rr = row & 255;
    int tloc = k8s >> 3;
    int sh = (k8s >> 2) & 1;
    int k8l = k8s & 3;
    size_t unit = (size_t)(k8l * 256 + rr) * 8;
#pragma unroll
    for (int e = 0; e < 3; ++e) {
        int T = e * 16 + tloc;
        size_t off = (size_t)(p * 96 + T * 2 + sh) * 8192 + unit;
        shortx8 val = (LO == 1) ? (e == 1 ? lv : hv) : (e == 2 ? lv : hv);
        *(shortx8*)&dst[off] = val;
    }
}

// ---------------------------------------------------------------------------
// 8-phase 256x256 pipelined bf16 GEMM. KT = K'/64 tiles (must be even).
// Grid = (M/256)*(N/256) = 256 blocks, 512 threads.
// ---------------------------------------------------------------------------
template <int KT>
__global__ __launch_bounds__(512, 2) void gemm_8ph(
    const unsigned short* __restrict__ Ap,
    const unsigned short* __restrict__ Bp,
    float* __restrict__ C, int ldc)
{
    __shared__ unsigned short lds[65536];   // 128KB: [slot][A|B][kh][k8l*256+row]*8

    const int tid = threadIdx.x;
    const int lane = tid & 63;
    const int w = tid >> 6;                 // 0..7
    const int wm = w >> 2, wn = w & 3;      // 2 x 4
    const int l15 = lane & 15, l4 = lane >> 4;

    int id = blockIdx.x;
    id = (id & 7) * 32 + (id >> 3);         // bijective XCD swizzle (256 blocks)
    const int bm = id >> 4, bn = id & 15;

    const unsigned short* ga = Ap + (size_t)bm * KT * 16384;
    const unsigned short* gb = Bp + (size_t)bn * KT * 16384;

    const int rA = (l4 * 256 + wm * 128 + l15) * 8;   // + frag*128 + s*8192 + slot
    const int rB = (l4 * 256 + wn * 64 + l15) * 8;    // + frag*128 + 16384 + ...

    floatx4 acc[8][4] = {};
    shortx8 bfr[4];

    // stage one 16KB region: slot=(vt&1), ab in {0=A,1=B}, s = k-half
    auto STAGE = [&](int vt, int ab, int s) {
        int T = vt < KT ? vt : KT - 1;     // virtual tiles clamp source (counts stay exact)
        const unsigned short* src = (ab ? gb : ga) + ((size_t)T * 2 + s) * 8192 + tid * 8;
        unsigned short* dst = (unsigned short*)lds + (vt & 1) * 32768 + ab * 16384 + s * 8192 + tid * 8;
        async_ld16(src, dst);
        async_ld16(src + 4096, dst + 4096);
    };

#define MFMA16(MH)                                                                             \
    acc[(MH)*4+0][0] = __builtin_amdgcn_mfma_f32_16x16x32_bf16(af0, bfr[0], acc[(MH)*4+0][0], 0,0,0); \
    acc[(MH)*4+0][1] = __builtin_amdgcn_mfma_f32_16x16x32_bf16(af0, bfr[1], acc[(MH)*4+0][1], 0,0,0); \
    acc[(MH)*4+0][2] = __builtin_amdgcn_mfma_f32_16x16x32_bf16(af0, bfr[2], acc[(MH)*4+0][2], 0,0,0); \
    acc[(MH)*4+0][3] = __builtin_amdgcn_mfma_f32_16x16x32_bf16(af0, bfr[3], acc[(MH)*4+0][3], 0,0,0); \
    acc[(MH)*4+1][0] = __builtin_amdgcn_mfma_f32_16x16x32_bf16(af1, bfr[0], acc[(MH)*4+1][0], 0,0,0); \
    acc[(MH)*4+1][1] = __builtin_amdgcn_mfma_f32_16x16x32_bf16(af1, bfr[1], acc[(MH)*4+1][1], 0,0,0); \
    acc[(MH)*4+1][2] = __builtin_amdgcn_mfma_f32_16x16x32_bf16(af1, bfr[2], acc[(MH)*4+1][2], 0,0,0); \
    acc[(MH)*4+1][3] = __builtin_amdgcn_mfma_f32_16x16x32_bf16(af1, bfr[3], acc[(MH)*4+1][3], 0,0,0); \
    acc[(MH)*4+2][0] = __builtin_amdgcn_mfma_f32_16x16x32_bf16(af2, bfr[0], acc[(MH)*4+2][0], 0,0,0); \
    acc[(MH)*4+2][1] = __builtin_amdgcn_mfma_f32_16x16x32_bf16(af2, bfr[1], acc[(MH)*4+2][1], 0,0,0); \
    acc[(MH)*4+2][2] = __builtin_amdgcn_mfma_f32_16x16x32_bf16(af2, bfr[2], acc[(MH)*4+2][2], 0,0,0); \
    acc[(MH)*4+2][3] = __builtin_amdgcn_mfma_f32_16x16x32_bf16(af2, bfr[3], acc[(MH)*4+2][3], 0,0,0); \
    acc[(MH)*4+3][0] = __builtin_amdgcn_mfma_f32_16x16x32_bf16(af3, bfr[0], acc[(MH)*4+3][0], 0,0,0); \
    acc[(MH)*4+3][1] = __builtin_amdgcn_mfma_f32_16x16x32_bf16(af3, bfr[1], acc[(MH)*4+3][1], 0,0,0); \
    acc[(MH)*4+3][2] = __builtin_amdgcn_mfma_f32_16x16x32_bf16(af3, bfr[2], acc[(MH)*4+3][2], 0,0,0); \
    acc[(MH)*4+3][3] = __builtin_amdgcn_mfma_f32_16x16x32_bf16(af3, bfr[3], acc[(MH)*4+3][3], 0,0,0);

#define PHASE(SLOT, S, MH, SVT, SAB, SS, DO_VM)                                \
    {                                                                          \
        const unsigned short* Ab = &lds[(SLOT)*32768 + (S)*8192] + rA;         \
        shortx8 af0 = *(const shortx8*)&Ab[((MH)*4 + 0) * 128];                \
        shortx8 af1 = *(const shortx8*)&Ab[((MH)*4 + 1) * 128];                \
        shortx8 af2 = *(const shortx8*)&Ab[((MH)*4 + 2) * 128];                \
        shortx8 af3 = *(const shortx8*)&Ab[((MH)*4 + 3) * 128];                \
        if ((MH) == 0) {                                                       \
            const unsigned short* Bb = &lds[(SLOT)*32768 + 16384 + (S)*8192] + rB; \
            bfr[0] = *(const shortx8*)&Bb[0];                                  \
            bfr[1] = *(const shortx8*)&Bb[128];                                \
            bfr[2] = *(const shortx8*)&Bb[256];                                \
            bfr[3] = *(const shortx8*)&Bb[384];                                \
        }                                                                      \
        STAGE(SVT, SAB, SS);                                                   \
        __builtin_amdgcn_s_barrier();                                          \
        asm volatile("s_waitcnt lgkmcnt(0)" ::: "memory");                     \
        __builtin_amdgcn_s_setprio(1);                                         \
        MFMA16(MH)                                                             \
        __builtin_amdgcn_s_setprio(0);                                         \
        if (DO_VM) { asm volatile("s_waitcnt vmcnt(8)" ::: "memory"); }        \
        __builtin_amdgcn_s_barrier();                                          \
    }

    // prologue: t0 all 4 regions + t1 first 2, in consumption order
    STAGE(0, 0, 0); STAGE(0, 1, 0); STAGE(0, 0, 1); STAGE(0, 1, 1);
    STAGE(1, 0, 0); STAGE(1, 1, 0);
    asm volatile("s_waitcnt vmcnt(8)" ::: "memory");   // t0 kh0 (A+B) landed
    __builtin_amdgcn_s_barrier();

#pragma unroll 1
    for (int i = 0; i < KT / 2; ++i) {
        const int t2 = 2 * i;
        PHASE(0, 0, 0, t2 + 1, 0, 1, 0)   // read t(2i) s0 mh0 ; stage (2i+1).A-kh1
        PHASE(0, 0, 1, t2 + 1, 1, 1, 1)   //                    stage (2i+1).B-kh1
        PHASE(0, 1, 0, t2 + 2, 0, 0, 0)   // read t(2i) s1     ; stage (2i+2).A-kh0
        PHASE(0, 1, 1, t2 + 2, 1, 0, 1)   //                    stage (2i+2).B-kh0
        PHASE(1, 0, 0, t2 + 2, 0, 1, 0)   // read t(2i+1) s0   ; stage (2i+2).A-kh1
        PHASE(1, 0, 1, t2 + 2, 1, 1, 1)   //                    stage (2i+2).B-kh1
        PHASE(1, 1, 0, t2 + 3, 0, 0, 0)   // read t(2i+1) s1   ; stage (2i+3).A-kh0
        PHASE(1, 1, 1, t2 + 3, 1, 0, 1)   //                    stage (2i+3).B-kh0
    }

#undef PHASE
#undef MFMA16

    // epilogue: C/D 16x16: col = lane&15, row = (lane>>4)*4 + reg (m89)
    const int c0 = bn * 256 + wn * 64;
    const int r0 = bm * 256 + wm * 128;
#pragma unroll
    for (int fi = 0; fi < 8; ++fi) {
#pragma unroll
        for (int fj = 0; fj < 4; ++fj) {
            int col = c0 + fj * 16 + l15;
            int rowb = r0 + fi * 16 + l4 * 4;
#pragma unroll
            for (int ri = 0; ri < 4; ++ri)
                C[(size_t)(rowb + ri) * ldc + col] = acc[fi][fj][ri];
        }
    }
}

// ---------------------------------------------------------------------------
// bf16 MFMA GEMM (R8 structure) -- out_proj (control this round).
// ---------------------------------------------------------------------------
template <int BN, int KP>
__global__ __launch_bounds__(256) void gemm_bf16_nt(
    const unsigned short* __restrict__ A,
    const unsigned short* __restrict__ Bm,
    float* __restrict__ C, int ldc)
{
    constexpr int TN32 = BN / 64;                 // 32-wide n-tiles per wave
    __shared__ unsigned short As[2 * 8192];       // [seg][t][128 rows][32 k]
    __shared__ unsigned short Bs[2 * BN * 64];    // [seg][t][BN rows][32 k]

    const int tid = threadIdx.x;
    const int w = tid >> 6;
    const int lane = tid & 63;
    const int wm = w >> 1, wn = w & 1;
    const int m0 = blockIdx.y * 128;
    const int n0 = blockIdx.x * BN;

    const int r4 = lane >> 2;                        // staging row in 16-group
    const int csw = (lane & 3) ^ ((r4 >> 1) & 3);    // swizzled source chunk
    const int gk = csw * 8;                          // shorts offset
    const int l31 = lane & 31;
    const int khalf = lane >> 5;                     // 0/1: k-half within 16
    const int rsw = (l31 >> 1) & 3;                  // read-side swizzle key

    floatx16 acc[2][TN32] = {};

    for (int k0 = 0; k0 < KP; k0 += 64) {
#pragma unroll
        for (int seg = 0; seg < 2; ++seg) {
            const unsigned short* Asrc = A + seg * KP;
            const unsigned short* Bsrc = Bm + seg * KP;
#pragma unroll
            for (int t = 0; t < 2; ++t) {
#pragma unroll
                for (int jj = 0; jj < 2; ++jj) {
                    int j = w + jj * 4;
                    async_ld16(Asrc + (size_t)(m0 + j * 16 + r4) * (2 * KP) + k0 + t * 32 + gk,
                               &As[seg * 8192 + t * 4096 + j * 512]);
                }
#pragma unroll
                for (int jj = 0; jj < BN / 64; ++jj) {
                    int j = w + jj * 4;
                    async_ld16(Bsrc + (size_t)(n0 + j * 16 + r4) * (2 * KP) + k0 + t * 32 + gk,
                               &Bs[seg * BN * 64 + t * BN * 32 + j * 512]);
                }
            }
        }
        __syncthreads();

#pragma unroll
        for (int t = 0; t < 2; ++t) {
#pragma unroll
            for (int kk = 0; kk < 2; ++kk) {
                const int pos = ((kk * 2 + khalf) ^ rsw) << 3;
                shortx8 ah[2], al[2], bh[TN32], bl[TN32];
#pragma unroll
                for (int i = 0; i < 2; ++i) {
                    int row = wm * 64 + i * 32 + l31;
                    ah[i] = *(const shortx8*)&As[t * 4096 + row * 32 + pos];
                    al[i] = *(const shortx8*)&As[8192 + t * 4096 + row * 32 + pos];
                }
#pragma unroll
                for (int j = 0; j < TN32; ++j) {
                    int col = wn * (BN / 2) + j * 32 + l31;
                    bh[j] = *(const shortx8*)&Bs[t * BN * 32 + col * 32 + pos];
                    bl[j] = *(const shortx8*)&Bs[BN * 64 + t * BN * 32 + col * 32 + pos];
                }
#pragma unroll
                for (int i = 0; i < 2; ++i)
#pragma unroll
                    for (int j = 0; j < TN32; ++j) {
                        acc[i][j] = __builtin_amdgcn_mfma_f32_32x32x16_bf16(ah[i], bh[j], acc[i][j], 0, 0, 0);
                        acc[i][j] = __builtin_amdgcn_mfma_f32_32x32x16_bf16(ah[i], bl[j], acc[i][j], 0, 0, 0);
                        acc[i][j] = __builtin_amdgcn_mfma_f32_32x32x16_bf16(al[i], bh[j], acc[i][j], 0, 0, 0);
                    }
            }
        }
        __syncthreads();
    }

#pragma unroll
    for (int i = 0; i < 2; ++i) {
#pragma unroll
        for (int j = 0; j < TN32; ++j) {
            int col = n0 + wn * (BN / 2) + j * 32 + l31;
#pragma unroll
            for (int r = 0; r < 16; ++r) {
                int row = m0 + wm * 64 + i * 32 + (r & 3) + 8 * (r >> 2) + 4 * khalf;
                C[(size_t)row * ldc + col] = acc[i][j][r];
            }
        }
    }
}

// ---------------------------------------------------------------------------
// fp32 -> 2-segment split-bf16: row = [hi (K) | lo (K)], stride 2K (out_proj)
// ---------------------------------------------------------------------------
__global__ __launch_bounds__(256) void split2_kernel(
    const float* __restrict__ src, unsigned short* __restrict__ dst, int K)
{
    int i = blockIdx.x * 256 + threadIdx.x;
    int m = i / K;
    int k = i - m * K;
    float a = src[i];
    __hip_bfloat16 h = __float2bfloat16(a);
    __hip_bfloat16 l = __float2bfloat16(a - __bfloat162float(h));
    unsigned short* row = dst + (size_t)m * 2 * K;
    row[k] = *(unsigned short*)&h;
    row[K + k] = *(unsigned short*)&l;
}

// ---------------------------------------------------------------------------
// x_proj split-K partial GEMM + reduce
// ---------------------------------------------------------------------------
__global__ __launch_bounds__(256) void xproj_splitk(
    const float* __restrict__ u, const float* __restrict__ Wx,
    float* __restrict__ Cp)
{
    __shared__ float As[16][68];
    __shared__ float Bs[16][100];

    const int tid = threadIdx.x;
    const int ks = blockIdx.x;
    const int m0 = blockIdx.y * 64;
    const int tx = tid & 15;
    const int ty = tid >> 4;

    float acc[4][6] = {};

    const int arow = tid >> 2;
    const int akk = (tid & 3) * 4;

    for (int k0 = ks * KC; k0 < (ks + 1) * KC; k0 += 16) {
        {
            float4 v = *(const float4*)&u[(size_t)(m0 + arow) * DINNER + k0 + akk];
            As[akk + 0][arow] = v.x;
            As[akk + 1][arow] = v.y;
            As[akk + 2][arow] = v.z;
            As[akk + 3][arow] = v.w;
        }
        for (int idx = tid; idx < 384; idx += 256) {
            int row = idx >> 2;
            int kk = (idx & 3) * 4;
            float4 v = *(const float4*)&Wx[(size_t)row * DINNER + k0 + kk];
            Bs[kk + 0][row] = v.x;
            Bs[kk + 1][row] = v.y;
            Bs[kk + 2][row] = v.z;
            Bs[kk + 3][row] = v.w;
        }
        __syncthreads();

#pragma unroll
        for (int k = 0; k < 16; ++k) {
            float a[4], b[6];
#pragma unroll
            for (int i = 0; i < 4; ++i) a[i] = As[k][ty * 4 + i];
#pragma unroll
            for (int j = 0; j < 6; ++j) b[j] = Bs[k][tx * 6 + j];
#pragma unroll
            for (int i = 0; i < 4; ++i)
#pragma unroll
                for (int j = 0; j < 6; ++j) acc[i][j] = fmaf(a[i], b[j], acc[i][j]);
        }
        __syncthreads();
    }

    float* outp = Cp + ((size_t)ks * M_ROWS + m0) * 96;
#pragma unroll
    for (int i = 0; i < 4; ++i)
#pragma unroll
        for (int j = 0; j < 6; ++j)
            outp[(ty * 4 + i) * 96 + tx * 6 + j] = acc[i][j];
}

__global__ __launch_bounds__(256) void xproj_reduce(
    const float* __restrict__ Cp, float* __restrict__ xdbl)
{
    int i = blockIdx.x * 256 + threadIdx.x;
    float s = 0.f;
#pragma unroll
    for (int c = 0; c < KSPLIT; ++c)
        s += Cp[(size_t)c * M_ROWS * 96 + i];
    xdbl[i] = s;
}

// ---------------------------------------------------------------------------
// fp32 GEMM (dt_proj, K=64)
// ---------------------------------------------------------------------------
template <int BM, int BN, int BK, int TM, int TN, bool BOUND_N, int EPI>
__global__ __launch_bounds__(256) void gemm_nt(
    const float* __restrict__ A, int lda,
    const float* __restrict__ Bmat, int ldb,
    float* __restrict__ C, int ldc,
    int M, int N, int K, const float* __restrict__ bias)
{
    __shared__ float As[BK][BM + 4];
    __shared__ float Bs[BK][BN + 4];

    const int tid = threadIdx.x;
    const int tx = tid % (BN / TN);
    const int ty = tid / (BN / TN);
    const int m0 = blockIdx.y * BM;
    const int n0 = blockIdx.x * BN;

    float acc[TM][TN];
#pragma unroll
    for (int i = 0; i < TM; ++i)
#pragma unroll
        for (int j = 0; j < TN; ++j) acc[i][j] = 0.f;

    for (int k0 = 0; k0 < K; k0 += BK) {
        for (int idx = tid * 4; idx < BM * BK; idx += 256 * 4) {
            int row = idx / BK;
            int kk = idx % BK;
            float4 v = *(const float4*)&A[(size_t)(m0 + row) * lda + k0 + kk];
            As[kk + 0][row] = v.x;
            As[kk + 1][row] = v.y;
            As[kk + 2][row] = v.z;
            As[kk + 3][row] = v.w;
        }
        for (int idx = tid * 4; idx < BN * BK; idx += 256 * 4) {
            int row = idx / BK;
            int kk = idx % BK;
            float4 v;
            if (!BOUND_N || (n0 + row) < N)
                v = *(const float4*)&Bmat[(size_t)(n0 + row) * ldb + k0 + kk];
            else
                v = make_float4(0.f, 0.f, 0.f, 0.f);
            Bs[kk + 0][row] = v.x;
            Bs[kk + 1][row] = v.y;
            Bs[kk + 2][row] = v.z;
            Bs[kk + 3][row] = v.w;
        }
        __syncthreads();

#pragma unroll
        for (int k = 0; k < BK; ++k) {
            float a[TM], b[TN];
#pragma unroll
            for (int i = 0; i < TM; ++i) a[i] = As[k][ty * TM + i];
#pragma unroll
            for (int j = 0; j < TN; ++j) b[j] = Bs[k][tx * TN + j];
#pragma unroll
            for (int i = 0; i < TM; ++i)
#pragma unroll
                for (int j = 0; j < TN; ++j) acc[i][j] = fmaf(a[i], b[j], acc[i][j]);
        }
        __syncthreads();
    }

#pragma unroll
    for (int i = 0; i < TM; ++i) {
        int m = m0 + ty * TM + i;
#pragma unroll
        for (int j = 0; j < TN; ++j) {
            int n = n0 + tx * TN + j;
            if (BOUND_N && n >= N) continue;
            float v = acc[i][j];
            if (EPI == 1) v = softplusf(v + bias[n]);
            C[(size_t)m * ldc + n] = v;
        }
    }
}

// ---------------------------------------------------------------------------
// conv + silu, float4 over channels
// ---------------------------------------------------------------------------
__global__ __launch_bounds__(256) void conv_silu_v4(
    const float* __restrict__ xz, const float* __restrict__ cw,
    const float* __restrict__ cb, float* __restrict__ u)
{
    int i = blockIdx.x * 256 + threadIdx.x;      // over M_ROWS * 512
    int dq = (i & 511) << 2;
    int bl = i >> 9;
    int b = bl >> 11;
    int l = bl & 2047;

    float4 W0 = *(const float4*)&cw[(dq + 0) * 4];
    float4 W1 = *(const float4*)&cw[(dq + 1) * 4];
    float4 W2 = *(const float4*)&cw[(dq + 2) * 4];
    float4 W3 = *(const float4*)&cw[(dq + 3) * 4];
    float4 acc = *(const float4*)&cb[dq];

#pragma unroll
    for (int k = 0; k < 4; ++k) {
        int ls = l + k - 3;
        if (ls >= 0) {
            float4 v = *(const float4*)&xz[((size_t)(b << 11) + ls) * 4096 + dq];
            acc.x = fmaf(v.x, ((const float*)&W0)[k], acc.x);
            acc.y = fmaf(v.y, ((const float*)&W1)[k], acc.y);
            acc.z = fmaf(v.z, ((const float*)&W2)[k], acc.z);
            acc.w = fmaf(v.w, ((const float*)&W3)[k], acc.w);
        }
    }
    float4 r = make_float4(siluf(acc.x), siluf(acc.y), siluf(acc.z), siluf(acc.w));
    *(float4*)&u[(size_t)bl * DINNER + dq] = r;
}

// ---------------------------------------------------------------------------
// Chunked selective scan (3 passes). PASS3 fuses gate + split-bf16 y2.
// ---------------------------------------------------------------------------
template <bool PASS3>
__global__ __launch_bounds__(256) void scan_chunk(
    const float* __restrict__ dbuf, const float* __restrict__ ubuf,
    const float* __restrict__ xdbl, const float* __restrict__ A_log,
    const float* __restrict__ Dv,
    float* __restrict__ Pbuf, float* __restrict__ Sbuf,
    const float* __restrict__ xz, unsigned short* __restrict__ y2)
{
    __shared__ float sd[16][CPB];
    __shared__ float su[16][CPB];
    __shared__ float sB[16][DSTATE];
    __shared__ float sC[16][DSTATE];

    const int tid = threadIdx.x;
    const int c    = blockIdx.x % CH;
    const int dblk = (blockIdx.x / CH) % (DINNER / CPB);
    const int b    = blockIdx.x / (CH * (DINNER / CPB));
    const int d0 = dblk * CPB;
    const int dg = tid >> 2;
    const int q  = tid & 3;
    const int d  = d0 + dg;
    const size_t base_bl = (size_t)b * L_SZ + (size_t)c * CLEN;

    float Ac[4], h[4];
    float sdl = 0.f;
#pragma unroll
    for (int j = 0; j < 4; ++j)
        Ac[j] = -expf(A_log[d * DSTATE + 4 * q + j]);
    const size_t psoff = (((size_t)b * CH + c) * DINNER + d0) * DSTATE + (size_t)tid * 4;
    if (PASS3) {
        float4 h0 = *(const float4*)&Sbuf[psoff];
        h[0] = h0.x; h[1] = h0.y; h[2] = h0.z; h[3] = h0.w;
    } else {
        h[0] = h[1] = h[2] = h[3] = 0.f;
    }
    const float Dd = PASS3 ? Dv[d] : 0.f;

    const int ls = tid >> 4;
    const int g4 = (tid & 15) * 4;
    const int ln = tid & 15;

    float4 r_d = *(const float4*)&dbuf[(base_bl + ls) * DINNER + d0 + g4];
    float4 r_u = *(const float4*)&ubuf[(base_bl + ls) * DINNER + d0 + g4];
    float r_B = xdbl[(base_bl + ls) * 96 + 64 + ln];
    float r_C = xdbl[(base_bl + ls) * 96 + 80 + ln];

    for (int l0 = 0; l0 < CLEN; l0 += 16) {
        __syncthreads();
        *(float4*)&sd[ls][g4] = r_d;
        *(float4*)&su[ls][g4] = r_u;
        sB[ls][ln] = r_B;
        sC[ls][ln] = r_C;
        __syncthreads();

        if (l0 + 16 < CLEN) {
            r_d = *(const float4*)&dbuf[(base_bl + l0 + 16 + ls) * DINNER + d0 + g4];
            r_u = *(const float4*)&ubuf[(base_bl + l0 + 16 + ls) * DINNER + d0 + g4];
            r_B = xdbl[(base_bl + l0 + 16 + ls) * 96 + 64 + ln];
            r_C = xdbl[(base_bl + l0 + 16 + ls) * 96 + 80 + ln];
        }

#pragma unroll
        for (int s = 0; s < 16; ++s) {
            float dl = sd[s][dg];
            float ul = su[s][dg];
            float4 Bv = *(float4*)&sB[s][4 * q];
            float dbu = dl * ul;
            float dA0 = expf(dl * Ac[0]);
            float dA1 = expf(dl * Ac[1]);
            float dA2 = expf(dl * Ac[2]);
            float dA3 = expf(dl * Ac[3]);
            h[0] = fmaf(dA0, h[0], dbu * Bv.x);
            h[1] = fmaf(dA1, h[1], dbu * Bv.y);
            h[2] = fmaf(dA2, h[2], dbu * Bv.z);
            h[3] = fmaf(dA3, h[3], dbu * Bv.w);
            if (!PASS3) {
                sdl += dl;
            } else {
                float4 Cv = *(float4*)&sC[s][4 * q];
                float y = h[0] * Cv.x + h[1] * Cv.y + h[2] * Cv.z + h[3] * Cv.w;
                y += __shfl_xor(y, 1);
                y += __shfl_xor(y, 2);
                if (q == 0) su[s][dg] = fmaf(ul, Dd, y);
            }
        }

        if (PASS3) {
            __syncthreads();
            size_t row = base_bl + l0 + ls;
            float4 yv = *(float4*)&su[ls][g4];
            float4 rv = *(const float4*)&xz[row * 4096 + 2048 + d0 + g4];
            float a0 = yv.x * siluf(rv.x);
            float a1 = yv.y * siluf(rv.y);
            float a2 = yv.z * siluf(rv.z);
            float a3 = yv.w * siluf(rv.w);
            __hip_bfloat16 h0 = __float2bfloat16(a0), h1 = __float2bfloat16(a1);
            __hip_bfloat16 h2 = __float2bfloat16(a2), h3 = __float2bfloat16(a3);
            __hip_bfloat16 l0b = __float2bfloat16(a0 - __bfloat162float(h0));
            __hip_bfloat16 l1b = __float2bfloat16(a1 - __bfloat162float(h1));
            __hip_bfloat16 l2b = __float2bfloat16(a2 - __bfloat162float(h2));
            __hip_bfloat16 l3b = __float2bfloat16(a3 - __bfloat162float(h3));
            ushort4 hv = make_ushort4(*(unsigned short*)&h0, *(unsigned short*)&h1,
                                      *(unsigned short*)&h2, *(unsigned short*)&h3);
            ushort4 lv = make_ushort4(*(unsigned short*)&l0b, *(unsigned short*)&l1b,
                                      *(unsigned short*)&l2b, *(unsigned short*)&l3b);
            unsigned short* yrow = y2 + row * 2 * DINNER + d0 + g4;
            *(ushort4*)&yrow[0] = hv;
            *(ushort4*)&yrow[DINNER] = lv;
        }
    }

    if (!PASS3) {
        *(float4*)&Pbuf[psoff] = make_float4(expf(Ac[0] * sdl), expf(Ac[1] * sdl),
                                             expf(Ac[2] * sdl), expf(Ac[3] * sdl));
        *(float4*)&Sbuf[psoff] = make_float4(h[0], h[1], h[2], h[3]);
    }
}

__global__ __launch_bounds__(256) void scan_combine(
    const float* __restrict__ Pbuf, float* __restrict__ Sbuf)
{
    int t = blockIdx.x * 256 + threadIdx.x;
    int b = t >> 15;
    int rem = t & 32767;
    size_t base = (size_t)b * CH * DINNER * DSTATE + rem;
    float H = 0.f;
#pragma unroll 4
    for (int c = 0; c < CH; ++c) {
        size_t off = base + (size_t)c * DINNER * DSTATE;
        float S = Sbuf[off];
        float P = Pbuf[off];
        Sbuf[off] = H;
        H = fmaf(P, H, S);
    }
}

// ---------------------------------------------------------------------------
extern "C" void kernel_launch(void* const* d_in, const int* in_sizes, int n_in,
                              void* d_out, int out_size, void* d_ws, size_t ws_size,
                              hipStream_t stream)
{
    const float* x          = (const float*)d_in[0];
    const float* in_proj_w  = (const float*)d_in[1];
    const float* conv_w     = (const float*)d_in[2];
    const float* conv_b     = (const float*)d_in[3];
    const float* x_proj_w   = (const float*)d_in[4];
    const float* dt_proj_w  = (const float*)d_in[5];
    const float* dt_proj_b  = (const float*)d_in[6];
    const float* A_log      = (const float*)d_in[7];
    const float* Dv         = (const float*)d_in[8];
    const float* out_proj_w = (const float*)d_in[9];
    float* out = (float*)d_out;

    // workspace layout (bytes):
    char* w = (char*)d_ws;
    float* xz   = (float*)(w);                       // 64 MB
    float* u    = (float*)(w + 67108864);            // 32 MB (written step 3)
    float* dbuf = (float*)(w + 100663296);           // 32 MB (written step 5)
    float* xdbl = (float*)(w + 134217728);           // 1.5 MB
    float* Pbuf = (float*)(w + 135790592);           // 8 MB
    float* Sbuf = (float*)(w + 144179200);           // 8 MB (ends 152567808)
    unsigned short* y2  = (unsigned short*)(w + 152567808);   // 32 MB (stage 6+)
    unsigned short* w2b = (unsigned short*)(w + 135790592);   // 8 MB over Pbuf (dead at 7)
    float* Cp = (float*)(w + 152567808);             // xproj partials (dead at 4, pre-y2)
    // panelized 3-seg bf16 inputs for in_proj; ALIAS u / dbuf (dead after step 2)
    unsigned short* x2p  = (unsigned short*)(w + 67108864);   // 24 MB over u
    unsigned short* w2ap = (unsigned short*)(w + 100663296);  // 24 MB over dbuf

    // 1) split x / in_proj_w to 3-segment panelized bf16 (K' = 3072, LDS-image order)
    split3_kernel<1><<<2048, 256, 0, stream>>>(x, x2p);          // [h,l,h]
    split3_kernel<2><<<2048, 256, 0, stream>>>(in_proj_w, w2ap); // [h,h,l]
    // 2) in_proj via 8-phase 256^2 pipelined MFMA GEMM (KT=48)
    gemm_8ph<48><<<256, 512, 0, stream>>>(x2p, w2ap, xz, 4096);
    // 3) conv + silu -> u (overwrites x2p, dead)
    conv_silu_v4<<<(M_ROWS * 512) / 256, 256, 0, stream>>>(xz, conv_w, conv_b, u);
    // 4) x_proj via split-K
    {
        dim3 g(KSPLIT, M_ROWS / 64);
        xproj_splitk<<<g, 256, 0, stream>>>(u, x_proj_w, Cp);
        xproj_reduce<<<(M_ROWS * 96) / 256, 256, 0, stream>>>(Cp, xdbl);
    }
    // 5) dt_proj + softplus -> dbuf (fp32, K=64; overwrites w2ap, dead)
    {
        dim3 g(2048 / 128, M_ROWS / 128);
        gemm_nt<128, 128, 16, 8, 8, false, 1><<<g, 256, 0, stream>>>(
            xdbl, 96, dt_proj_w, 64, dbuf, 2048, M_ROWS, 2048, 64, dt_proj_b);
    }
    // 6) chunked selective scan; pass3 fuses gate + split into y2
    {
        const int nblk = B_SZ * (DINNER / CPB) * CH;
        scan_chunk<false><<<nblk, 256, 0, stream>>>(dbuf, u, xdbl, A_log, Dv, Pbuf, Sbuf, nullptr, nullptr);
        scan_combine<<<B_SZ * DINNER * DSTATE / 256, 256, 0, stream>>>(Pbuf, Sbuf);
        scan_chunk<true><<<nblk, 256, 0, stream>>>(dbuf, u, xdbl, A_log, Dv, nullptr, Sbuf, xz, y2);
    }
    // 7) split out_proj_w (2-seg, old path)
    split2_kernel<<<(DMODEL * DINNER) / 256, 256, 0, stream>>>(out_proj_w, w2b, DINNER);
    // 8) out_proj via 32x32x16 MFMA (R8 structure, control)
    {
        dim3 g(1024 / 64, M_ROWS / 128);
        gemm_bf16_nt<64, 2048><<<g, 256, 0, stream>>>(y2, w2b, out, 1024);
    }
}

// Round 4
// 500.797 us; speedup vs baseline: 1.2258x; 1.2258x over previous
//
#include <hip/hip_runtime.h>
#include <hip/hip_bf16.h>
#include <math.h>

#define B_SZ 2
#define L_SZ 2048
#define DMODEL 1024
#define DINNER 2048
#define DSTATE 16
#define DTRANK 64
#define M_ROWS (B_SZ * L_SZ)   // 4096

#define CH 32
#define CLEN (L_SZ / CH)
#define CPB 64

#define KSPLIT 8
#define KC (DINNER / KSPLIT)   // 256

typedef short shortx8 __attribute__((ext_vector_type(8)));
typedef float floatx4 __attribute__((ext_vector_type(4)));
typedef float floatx16 __attribute__((ext_vector_type(16)));

__device__ __forceinline__ float softplusf(float x) {
    return fmaxf(x, 0.f) + log1pf(expf(-fabsf(x)));
}
__device__ __forceinline__ float siluf(float x) {
    return x * (1.f / (1.f + expf(-x)));
}

__device__ __forceinline__ void async_ld16(const void* g, void* l) {
    __builtin_amdgcn_global_load_lds(
        (__attribute__((address_space(1))) void*)(unsigned long long)g,
        (__attribute__((address_space(3))) void*)(unsigned int)(unsigned long long)l,
        16, 0, 0);
}

// ---------------------------------------------------------------------------
// R13: ONLY change vs R12 = dt_proj rewritten (dtproj_kernel). gemm_nt was
// grid-limited (512 blocks = 2/CU, Occ 22%) with 4 staging rounds + 8 barriers
// fully exposed; measured 133us vs ~10-15us roofline for 1.07 GFLOP + 38MB.
// New: K=64 staged ONCE (A 64x64 + B 128x64 in LDS, k-major), 1 barrier,
// 1024 blocks (4/CU queued, 3 resident by 50KB LDS), TM4xTN8, fused
// bias+softplus epilogue, float4 stores. Everything else byte-identical
// (control for gemm_8ph, which should now surface in top-5).
// ---------------------------------------------------------------------------

// fp32 -> 3-segment panelized bf16 in LDS-image order.
// LO==1 (A/activations): segs [h, l, h];  LO==2 (B/weights): segs [h, h, l]
// => sum over K' = xh*wh + xl*wh + xh*wl  (same split-fp32 triple as R8).
template <int LO>
__global__ __launch_bounds__(256) void split3_kernel(
    const float* __restrict__ src, unsigned short* __restrict__ dst)
{
    int i = blockIdx.x * 256 + threadIdx.x;   // 4096 rows x 128 k8-groups
    int row = i & 4095;
    int k8s = i >> 12;                        // 0..127
    const float* s = src + (size_t)row * 1024 + k8s * 8;
    float4 v0 = *(const float4*)s;
    float4 v1 = *(const float4*)(s + 4);
    float vs[8] = {v0.x, v0.y, v0.z, v0.w, v1.x, v1.y, v1.z, v1.w};
    unsigned short hsv[8], lsv[8];
#pragma unroll
    for (int j = 0; j < 8; ++j) {
        __hip_bfloat16 h = __float2bfloat16(vs[j]);
        __hip_bfloat16 l = __float2bfloat16(vs[j] - __bfloat162float(h));
        hsv[j] = *(unsigned short*)&h;
        lsv[j] = *(unsigned short*)&l;
    }
    shortx8 hv = *(shortx8*)hsv;
    shortx8 lv = *(shortx8*)lsv;
    int p = row >> 8, rr = row & 255;
    int tloc = k8s >> 3;
    int sh = (k8s >> 2) & 1;
    int k8l = k8s & 3;
    size_t unit = (size_t)(k8l * 256 + rr) * 8;
#pragma unroll
    for (int e = 0; e < 3; ++e) {
        int T = e * 16 + tloc;
        size_t off = (size_t)(p * 96 + T * 2 + sh) * 8192 + unit;
        shortx8 val = (LO == 1) ? (e == 1 ? lv : hv) : (e == 2 ? lv : hv);
        *(shortx8*)&dst[off] = val;
    }
}

// ---------------------------------------------------------------------------
// 8-phase 256x256 pipelined bf16 GEMM. KT = K'/64 tiles (must be even).
// Grid = (M/256)*(N/256) = 256 blocks, 512 threads.
// ---------------------------------------------------------------------------
template <int KT>
__global__ __launch_bounds__(512, 2) void gemm_8ph(
    const unsigned short* __restrict__ Ap,
    const unsigned short* __restrict__ Bp,
    float* __restrict__ C, int ldc)
{
    __shared__ unsigned short lds[65536];   // 128KB: [slot][A|B][kh][k8l*256+row]*8

    const int tid = threadIdx.x;
    const int lane = tid & 63;
    const int w = tid >> 6;                 // 0..7
    const int wm = w >> 2, wn = w & 3;      // 2 x 4
    const int l15 = lane & 15, l4 = lane >> 4;

    int id = blockIdx.x;
    id = (id & 7) * 32 + (id >> 3);         // bijective XCD swizzle (256 blocks)
    const int bm = id >> 4, bn = id & 15;

    const unsigned short* ga = Ap + (size_t)bm * KT * 16384;
    const unsigned short* gb = Bp + (size_t)bn * KT * 16384;

    const int rA = (l4 * 256 + wm * 128 + l15) * 8;   // + frag*128 + s*8192 + slot
    const int rB = (l4 * 256 + wn * 64 + l15) * 8;    // + frag*128 + 16384 + ...

    floatx4 acc[8][4] = {};
    shortx8 bfr[4];

    // stage one 16KB region: slot=(vt&1), ab in {0=A,1=B}, s = k-half
    auto STAGE = [&](int vt, int ab, int s) {
        int T = vt < KT ? vt : KT - 1;     // virtual tiles clamp source (counts stay exact)
        const unsigned short* src = (ab ? gb : ga) + ((size_t)T * 2 + s) * 8192 + tid * 8;
        unsigned short* dst = (unsigned short*)lds + (vt & 1) * 32768 + ab * 16384 + s * 8192 + tid * 8;
        async_ld16(src, dst);
        async_ld16(src + 4096, dst + 4096);
    };

#define MFMA16(MH)                                                                             \
    acc[(MH)*4+0][0] = __builtin_amdgcn_mfma_f32_16x16x32_bf16(af0, bfr[0], acc[(MH)*4+0][0], 0,0,0); \
    acc[(MH)*4+0][1] = __builtin_amdgcn_mfma_f32_16x16x32_bf16(af0, bfr[1], acc[(MH)*4+0][1], 0,0,0); \
    acc[(MH)*4+0][2] = __builtin_amdgcn_mfma_f32_16x16x32_bf16(af0, bfr[2], acc[(MH)*4+0][2], 0,0,0); \
    acc[(MH)*4+0][3] = __builtin_amdgcn_mfma_f32_16x16x32_bf16(af0, bfr[3], acc[(MH)*4+0][3], 0,0,0); \
    acc[(MH)*4+1][0] = __builtin_amdgcn_mfma_f32_16x16x32_bf16(af1, bfr[0], acc[(MH)*4+1][0], 0,0,0); \
    acc[(MH)*4+1][1] = __builtin_amdgcn_mfma_f32_16x16x32_bf16(af1, bfr[1], acc[(MH)*4+1][1], 0,0,0); \
    acc[(MH)*4+1][2] = __builtin_amdgcn_mfma_f32_16x16x32_bf16(af1, bfr[2], acc[(MH)*4+1][2], 0,0,0); \
    acc[(MH)*4+1][3] = __builtin_amdgcn_mfma_f32_16x16x32_bf16(af1, bfr[3], acc[(MH)*4+1][3], 0,0,0); \
    acc[(MH)*4+2][0] = __builtin_amdgcn_mfma_f32_16x16x32_bf16(af2, bfr[0], acc[(MH)*4+2][0], 0,0,0); \
    acc[(MH)*4+2][1] = __builtin_amdgcn_mfma_f32_16x16x32_bf16(af2, bfr[1], acc[(MH)*4+2][1], 0,0,0); \
    acc[(MH)*4+2][2] = __builtin_amdgcn_mfma_f32_16x16x32_bf16(af2, bfr[2], acc[(MH)*4+2][2], 0,0,0); \
    acc[(MH)*4+2][3] = __builtin_amdgcn_mfma_f32_16x16x32_bf16(af2, bfr[3], acc[(MH)*4+2][3], 0,0,0); \
    acc[(MH)*4+3][0] = __builtin_amdgcn_mfma_f32_16x16x32_bf16(af3, bfr[0], acc[(MH)*4+3][0], 0,0,0); \
    acc[(MH)*4+3][1] = __builtin_amdgcn_mfma_f32_16x16x32_bf16(af3, bfr[1], acc[(MH)*4+3][1], 0,0,0); \
    acc[(MH)*4+3][2] = __builtin_amdgcn_mfma_f32_16x16x32_bf16(af3, bfr[2], acc[(MH)*4+3][2], 0,0,0); \
    acc[(MH)*4+3][3] = __builtin_amdgcn_mfma_f32_16x16x32_bf16(af3, bfr[3], acc[(MH)*4+3][3], 0,0,0);

#define PHASE(SLOT, S, MH, SVT, SAB, SS, DO_VM)                                \
    {                                                                          \
        const unsigned short* Ab = &lds[(SLOT)*32768 + (S)*8192] + rA;         \
        shortx8 af0 = *(const shortx8*)&Ab[((MH)*4 + 0) * 128];                \
        shortx8 af1 = *(const shortx8*)&Ab[((MH)*4 + 1) * 128];                \
        shortx8 af2 = *(const shortx8*)&Ab[((MH)*4 + 2) * 128];                \
        shortx8 af3 = *(const shortx8*)&Ab[((MH)*4 + 3) * 128];                \
        if ((MH) == 0) {                                                       \
            const unsigned short* Bb = &lds[(SLOT)*32768 + 16384 + (S)*8192] + rB; \
            bfr[0] = *(const shortx8*)&Bb[0];                                  \
            bfr[1] = *(const shortx8*)&Bb[128];                                \
            bfr[2] = *(const shortx8*)&Bb[256];                                \
            bfr[3] = *(const shortx8*)&Bb[384];                                \
        }                                                                      \
        STAGE(SVT, SAB, SS);                                                   \
        __builtin_amdgcn_s_barrier();                                          \
        asm volatile("s_waitcnt lgkmcnt(0)" ::: "memory");                     \
        __builtin_amdgcn_s_setprio(1);                                         \
        MFMA16(MH)                                                             \
        __builtin_amdgcn_s_setprio(0);                                         \
        if (DO_VM) { asm volatile("s_waitcnt vmcnt(8)" ::: "memory"); }        \
        __builtin_amdgcn_s_barrier();                                          \
    }

    // prologue: t0 all 4 regions + t1 first 2, in consumption order
    STAGE(0, 0, 0); STAGE(0, 1, 0); STAGE(0, 0, 1); STAGE(0, 1, 1);
    STAGE(1, 0, 0); STAGE(1, 1, 0);
    asm volatile("s_waitcnt vmcnt(8)" ::: "memory");   // t0 kh0 (A+B) landed
    __builtin_amdgcn_s_barrier();

#pragma unroll 1
    for (int i = 0; i < KT / 2; ++i) {
        const int t2 = 2 * i;
        PHASE(0, 0, 0, t2 + 1, 0, 1, 0)   // read t(2i) s0 mh0 ; stage (2i+1).A-kh1
        PHASE(0, 0, 1, t2 + 1, 1, 1, 1)   //                    stage (2i+1).B-kh1
        PHASE(0, 1, 0, t2 + 2, 0, 0, 0)   // read t(2i) s1     ; stage (2i+2).A-kh0
        PHASE(0, 1, 1, t2 + 2, 1, 0, 1)   //                    stage (2i+2).B-kh0
        PHASE(1, 0, 0, t2 + 2, 0, 1, 0)   // read t(2i+1) s0   ; stage (2i+2).A-kh1
        PHASE(1, 0, 1, t2 + 2, 1, 1, 1)   //                    stage (2i+2).B-kh1
        PHASE(1, 1, 0, t2 + 3, 0, 0, 0)   // read t(2i+1) s1   ; stage (2i+3).A-kh0
        PHASE(1, 1, 1, t2 + 3, 1, 0, 1)   //                    stage (2i+3).B-kh0
    }

#undef PHASE
#undef MFMA16

    // epilogue: C/D 16x16: col = lane&15, row = (lane>>4)*4 + reg (m89)
    const int c0 = bn * 256 + wn * 64;
    const int r0 = bm * 256 + wm * 128;
#pragma unroll
    for (int fi = 0; fi < 8; ++fi) {
#pragma unroll
        for (int fj = 0; fj < 4; ++fj) {
            int col = c0 + fj * 16 + l15;
            int rowb = r0 + fi * 16 + l4 * 4;
#pragma unroll
            for (int ri = 0; ri < 4; ++ri)
                C[(size_t)(rowb + ri) * ldc + col] = acc[fi][fj][ri];
        }
    }
}

// ---------------------------------------------------------------------------
// bf16 MFMA GEMM (R8 structure) -- out_proj (control).
// ---------------------------------------------------------------------------
template <int BN, int KP>
__global__ __launch_bounds__(256) void gemm_bf16_nt(
    const unsigned short* __restrict__ A,
    const unsigned short* __restrict__ Bm,
    float* __restrict__ C, int ldc)
{
    constexpr int TN32 = BN / 64;                 // 32-wide n-tiles per wave
    __shared__ unsigned short As[2 * 8192];       // [seg][t][128 rows][32 k]
    __shared__ unsigned short Bs[2 * BN * 64];    // [seg][t][BN rows][32 k]

    const int tid = threadIdx.x;
    const int w = tid >> 6;
    const int lane = tid & 63;
    const int wm = w >> 1, wn = w & 1;
    const int m0 = blockIdx.y * 128;
    const int n0 = blockIdx.x * BN;

    const int r4 = lane >> 2;                        // staging row in 16-group
    const int csw = (lane & 3) ^ ((r4 >> 1) & 3);    // swizzled source chunk
    const int gk = csw * 8;                          // shorts offset
    const int l31 = lane & 31;
    const int khalf = lane >> 5;                     // 0/1: k-half within 16
    const int rsw = (l31 >> 1) & 3;                  // read-side swizzle key

    floatx16 acc[2][TN32] = {};

    for (int k0 = 0; k0 < KP; k0 += 64) {
#pragma unroll
        for (int seg = 0; seg < 2; ++seg) {
            const unsigned short* Asrc = A + seg * KP;
            const unsigned short* Bsrc = Bm + seg * KP;
#pragma unroll
            for (int t = 0; t < 2; ++t) {
#pragma unroll
                for (int jj = 0; jj < 2; ++jj) {
                    int j = w + jj * 4;
                    async_ld16(Asrc + (size_t)(m0 + j * 16 + r4) * (2 * KP) + k0 + t * 32 + gk,
                               &As[seg * 8192 + t * 4096 + j * 512]);
                }
#pragma unroll
                for (int jj = 0; jj < BN / 64; ++jj) {
                    int j = w + jj * 4;
                    async_ld16(Bsrc + (size_t)(n0 + j * 16 + r4) * (2 * KP) + k0 + t * 32 + gk,
                               &Bs[seg * BN * 64 + t * BN * 32 + j * 512]);
                }
            }
        }
        __syncthreads();

#pragma unroll
        for (int t = 0; t < 2; ++t) {
#pragma unroll
            for (int kk = 0; kk < 2; ++kk) {
                const int pos = ((kk * 2 + khalf) ^ rsw) << 3;
                shortx8 ah[2], al[2], bh[TN32], bl[TN32];
#pragma unroll
                for (int i = 0; i < 2; ++i) {
                    int row = wm * 64 + i * 32 + l31;
                    ah[i] = *(const shortx8*)&As[t * 4096 + row * 32 + pos];
                    al[i] = *(const shortx8*)&As[8192 + t * 4096 + row * 32 + pos];
                }
#pragma unroll
                for (int j = 0; j < TN32; ++j) {
                    int col = wn * (BN / 2) + j * 32 + l31;
                    bh[j] = *(const shortx8*)&Bs[t * BN * 32 + col * 32 + pos];
                    bl[j] = *(const shortx8*)&Bs[BN * 64 + t * BN * 32 + col * 32 + pos];
                }
#pragma unroll
                for (int i = 0; i < 2; ++i)
#pragma unroll
                    for (int j = 0; j < TN32; ++j) {
                        acc[i][j] = __builtin_amdgcn_mfma_f32_32x32x16_bf16(ah[i], bh[j], acc[i][j], 0, 0, 0);
                        acc[i][j] = __builtin_amdgcn_mfma_f32_32x32x16_bf16(ah[i], bl[j], acc[i][j], 0, 0, 0);
                        acc[i][j] = __builtin_amdgcn_mfma_f32_32x32x16_bf16(al[i], bh[j], acc[i][j], 0, 0, 0);
                    }
            }
        }
        __syncthreads();
    }

#pragma unroll
    for (int i = 0; i < 2; ++i) {
#pragma unroll
        for (int j = 0; j < TN32; ++j) {
            int col = n0 + wn * (BN / 2) + j * 32 + l31;
#pragma unroll
            for (int r = 0; r < 16; ++r) {
                int row = m0 + wm * 64 + i * 32 + (r & 3) + 8 * (r >> 2) + 4 * khalf;
                C[(size_t)row * ldc + col] = acc[i][j][r];
            }
        }
    }
}

// ---------------------------------------------------------------------------
// fp32 -> 2-segment split-bf16: row = [hi (K) | lo (K)], stride 2K (out_proj)
// ---------------------------------------------------------------------------
__global__ __launch_bounds__(256) void split2_kernel(
    const float* __restrict__ src, unsigned short* __restrict__ dst, int K)
{
    int i = blockIdx.x * 256 + threadIdx.x;
    int m = i / K;
    int k = i - m * K;
    float a = src[i];
    __hip_bfloat16 h = __float2bfloat16(a);
    __hip_bfloat16 l = __float2bfloat16(a - __bfloat162float(h));
    unsigned short* row = dst + (size_t)m * 2 * K;
    row[k] = *(unsigned short*)&h;
    row[K + k] = *(unsigned short*)&l;
}

// ---------------------------------------------------------------------------
// x_proj split-K partial GEMM + reduce
// ---------------------------------------------------------------------------
__global__ __launch_bounds__(256) void xproj_splitk(
    const float* __restrict__ u, const float* __restrict__ Wx,
    float* __restrict__ Cp)
{
    __shared__ float As[16][68];
    __shared__ float Bs[16][100];

    const int tid = threadIdx.x;
    const int ks = blockIdx.x;
    const int m0 = blockIdx.y * 64;
    const int tx = tid & 15;
    const int ty = tid >> 4;

    float acc[4][6] = {};

    const int arow = tid >> 2;
    const int akk = (tid & 3) * 4;

    for (int k0 = ks * KC; k0 < (ks + 1) * KC; k0 += 16) {
        {
            float4 v = *(const float4*)&u[(size_t)(m0 + arow) * DINNER + k0 + akk];
            As[akk + 0][arow] = v.x;
            As[akk + 1][arow] = v.y;
            As[akk + 2][arow] = v.z;
            As[akk + 3][arow] = v.w;
        }
        for (int idx = tid; idx < 384; idx += 256) {
            int row = idx >> 2;
            int kk = (idx & 3) * 4;
            float4 v = *(const float4*)&Wx[(size_t)row * DINNER + k0 + kk];
            Bs[kk + 0][row] = v.x;
            Bs[kk + 1][row] = v.y;
            Bs[kk + 2][row] = v.z;
            Bs[kk + 3][row] = v.w;
        }
        __syncthreads();

#pragma unroll
        for (int k = 0; k < 16; ++k) {
            float a[4], b[6];
#pragma unroll
            for (int i = 0; i < 4; ++i) a[i] = As[k][ty * 4 + i];
#pragma unroll
            for (int j = 0; j < 6; ++j) b[j] = Bs[k][tx * 6 + j];
#pragma unroll
            for (int i = 0; i < 4; ++i)
#pragma unroll
                for (int j = 0; j < 6; ++j) acc[i][j] = fmaf(a[i], b[j], acc[i][j]);
        }
        __syncthreads();
    }

    float* outp = Cp + ((size_t)ks * M_ROWS + m0) * 96;
#pragma unroll
    for (int i = 0; i < 4; ++i)
#pragma unroll
        for (int j = 0; j < 6; ++j)
            outp[(ty * 4 + i) * 96 + tx * 6 + j] = acc[i][j];
}

__global__ __launch_bounds__(256) void xproj_reduce(
    const float* __restrict__ Cp, float* __restrict__ xdbl)
{
    int i = blockIdx.x * 256 + threadIdx.x;
    float s = 0.f;
#pragma unroll
    for (int c = 0; c < KSPLIT; ++c)
        s += Cp[(size_t)c * M_ROWS * 96 + i];
    xdbl[i] = s;
}

// ---------------------------------------------------------------------------
// dt_proj + softplus, K=64 staged once. A = xdbl[:, :64] (lda 96),
// B = dt_proj_w [2048][64]. Tile 64(M) x 128(N), 256 thr, TM4 x TN8.
// ---------------------------------------------------------------------------
__global__ __launch_bounds__(256) void dtproj_kernel(
    const float* __restrict__ A, const float* __restrict__ Bw,
    const float* __restrict__ bias, float* __restrict__ Cout)
{
    __shared__ float As[64][68];     // [k][row], float4-aligned rows (272B)
    __shared__ float Bs[64][132];    // [k][row], float4-aligned rows (528B)

    const int tid = threadIdx.x;
    const int m0 = blockIdx.y * 64;
    const int n0 = blockIdx.x * 128;
    const int tx = tid & 15;         // 8 cols each
    const int ty = tid >> 4;         // 4 rows each

    // stage A: 64 rows x 64 k (k-major in LDS)
    for (int idx = tid * 4; idx < 64 * 64; idx += 1024) {
        int row = idx >> 6, kk = idx & 63;
        float4 v = *(const float4*)&A[(size_t)(m0 + row) * 96 + kk];
        As[kk + 0][row] = v.x;
        As[kk + 1][row] = v.y;
        As[kk + 2][row] = v.z;
        As[kk + 3][row] = v.w;
    }
    // stage B: 128 rows x 64 k
    for (int idx = tid * 4; idx < 128 * 64; idx += 1024) {
        int row = idx >> 6, kk = idx & 63;
        float4 v = *(const float4*)&Bw[(size_t)(n0 + row) * 64 + kk];
        Bs[kk + 0][row] = v.x;
        Bs[kk + 1][row] = v.y;
        Bs[kk + 2][row] = v.z;
        Bs[kk + 3][row] = v.w;
    }
    __syncthreads();

    float acc[4][8] = {};
#pragma unroll 8
    for (int k = 0; k < 64; ++k) {
        float a[4], b[8];
        *(float4*)a = *(const float4*)&As[k][ty * 4];
        *(float4*)&b[0] = *(const float4*)&Bs[k][tx * 8];
        *(float4*)&b[4] = *(const float4*)&Bs[k][tx * 8 + 4];
#pragma unroll
        for (int i = 0; i < 4; ++i)
#pragma unroll
            for (int j = 0; j < 8; ++j) acc[i][j] = fmaf(a[i], b[j], acc[i][j]);
    }

#pragma unroll
    for (int i = 0; i < 4; ++i) {
        int m = m0 + ty * 4 + i;
        float o[8];
#pragma unroll
        for (int j = 0; j < 8; ++j)
            o[j] = softplusf(acc[i][j] + bias[n0 + tx * 8 + j]);
        float* dst = &Cout[(size_t)m * DINNER + n0 + tx * 8];
        *(float4*)&dst[0] = *(float4*)&o[0];
        *(float4*)&dst[4] = *(float4*)&o[4];
    }
}

// ---------------------------------------------------------------------------
// conv + silu, float4 over channels
// ---------------------------------------------------------------------------
__global__ __launch_bounds__(256) void conv_silu_v4(
    const float* __restrict__ xz, const float* __restrict__ cw,
    const float* __restrict__ cb, float* __restrict__ u)
{
    int i = blockIdx.x * 256 + threadIdx.x;      // over M_ROWS * 512
    int dq = (i & 511) << 2;
    int bl = i >> 9;
    int b = bl >> 11;
    int l = bl & 2047;

    float4 W0 = *(const float4*)&cw[(dq + 0) * 4];
    float4 W1 = *(const float4*)&cw[(dq + 1) * 4];
    float4 W2 = *(const float4*)&cw[(dq + 2) * 4];
    float4 W3 = *(const float4*)&cw[(dq + 3) * 4];
    float4 acc = *(const float4*)&cb[dq];

#pragma unroll
    for (int k = 0; k < 4; ++k) {
        int ls = l + k - 3;
        if (ls >= 0) {
            float4 v = *(const float4*)&xz[((size_t)(b << 11) + ls) * 4096 + dq];
            acc.x = fmaf(v.x, ((const float*)&W0)[k], acc.x);
            acc.y = fmaf(v.y, ((const float*)&W1)[k], acc.y);
            acc.z = fmaf(v.z, ((const float*)&W2)[k], acc.z);
            acc.w = fmaf(v.w, ((const float*)&W3)[k], acc.w);
        }
    }
    float4 r = make_float4(siluf(acc.x), siluf(acc.y), siluf(acc.z), siluf(acc.w));
    *(float4*)&u[(size_t)bl * DINNER + dq] = r;
}

// ---------------------------------------------------------------------------
// Chunked selective scan (3 passes). PASS3 fuses gate + split-bf16 y2.
// ---------------------------------------------------------------------------
template <bool PASS3>
__global__ __launch_bounds__(256) void scan_chunk(
    const float* __restrict__ dbuf, const float* __restrict__ ubuf,
    const float* __restrict__ xdbl, const float* __restrict__ A_log,
    const float* __restrict__ Dv,
    float* __restrict__ Pbuf, float* __restrict__ Sbuf,
    const float* __restrict__ xz, unsigned short* __restrict__ y2)
{
    __shared__ float sd[16][CPB];
    __shared__ float su[16][CPB];
    __shared__ float sB[16][DSTATE];
    __shared__ float sC[16][DSTATE];

    const int tid = threadIdx.x;
    const int c    = blockIdx.x % CH;
    const int dblk = (blockIdx.x / CH) % (DINNER / CPB);
    const int b    = blockIdx.x / (CH * (DINNER / CPB));
    const int d0 = dblk * CPB;
    const int dg = tid >> 2;
    const int q  = tid & 3;
    const int d  = d0 + dg;
    const size_t base_bl = (size_t)b * L_SZ + (size_t)c * CLEN;

    float Ac[4], h[4];
    float sdl = 0.f;
#pragma unroll
    for (int j = 0; j < 4; ++j)
        Ac[j] = -expf(A_log[d * DSTATE + 4 * q + j]);
    const size_t psoff = (((size_t)b * CH + c) * DINNER + d0) * DSTATE + (size_t)tid * 4;
    if (PASS3) {
        float4 h0 = *(const float4*)&Sbuf[psoff];
        h[0] = h0.x; h[1] = h0.y; h[2] = h0.z; h[3] = h0.w;
    } else {
        h[0] = h[1] = h[2] = h[3] = 0.f;
    }
    const float Dd = PASS3 ? Dv[d] : 0.f;

    const int ls = tid >> 4;
    const int g4 = (tid & 15) * 4;
    const int ln = tid & 15;

    float4 r_d = *(const float4*)&dbuf[(base_bl + ls) * DINNER + d0 + g4];
    float4 r_u = *(const float4*)&ubuf[(base_bl + ls) * DINNER + d0 + g4];
    float r_B = xdbl[(base_bl + ls) * 96 + 64 + ln];
    float r_C = xdbl[(base_bl + ls) * 96 + 80 + ln];

    for (int l0 = 0; l0 < CLEN; l0 += 16) {
        __syncthreads();
        *(float4*)&sd[ls][g4] = r_d;
        *(float4*)&su[ls][g4] = r_u;
        sB[ls][ln] = r_B;
        sC[ls][ln] = r_C;
        __syncthreads();

        if (l0 + 16 < CLEN) {
            r_d = *(const float4*)&dbuf[(base_bl + l0 + 16 + ls) * DINNER + d0 + g4];
            r_u = *(const float4*)&ubuf[(base_bl + l0 + 16 + ls) * DINNER + d0 + g4];
            r_B = xdbl[(base_bl + l0 + 16 + ls) * 96 + 64 + ln];
            r_C = xdbl[(base_bl + l0 + 16 + ls) * 96 + 80 + ln];
        }

#pragma unroll
        for (int s = 0; s < 16; ++s) {
            float dl = sd[s][dg];
            float ul = su[s][dg];
            float4 Bv = *(float4*)&sB[s][4 * q];
            float dbu = dl * ul;
            float dA0 = expf(dl * Ac[0]);
            float dA1 = expf(dl * Ac[1]);
            float dA2 = expf(dl * Ac[2]);
            float dA3 = expf(dl * Ac[3]);
            h[0] = fmaf(dA0, h[0], dbu * Bv.x);
            h[1] = fmaf(dA1, h[1], dbu * Bv.y);
            h[2] = fmaf(dA2, h[2], dbu * Bv.z);
            h[3] = fmaf(dA3, h[3], dbu * Bv.w);
            if (!PASS3) {
                sdl += dl;
            } else {
                float4 Cv = *(float4*)&sC[s][4 * q];
                float y = h[0] * Cv.x + h[1] * Cv.y + h[2] * Cv.z + h[3] * Cv.w;
                y += __shfl_xor(y, 1);
                y += __shfl_xor(y, 2);
                if (q == 0) su[s][dg] = fmaf(ul, Dd, y);
            }
        }

        if (PASS3) {
            __syncthreads();
            size_t row = base_bl + l0 + ls;
            float4 yv = *(float4*)&su[ls][g4];
            float4 rv = *(const float4*)&xz[row * 4096 + 2048 + d0 + g4];
            float a0 = yv.x * siluf(rv.x);
            float a1 = yv.y * siluf(rv.y);
            float a2 = yv.z * siluf(rv.z);
            float a3 = yv.w * siluf(rv.w);
            __hip_bfloat16 h0 = __float2bfloat16(a0), h1 = __float2bfloat16(a1);
            __hip_bfloat16 h2 = __float2bfloat16(a2), h3 = __float2bfloat16(a3);
            __hip_bfloat16 l0b = __float2bfloat16(a0 - __bfloat162float(h0));
            __hip_bfloat16 l1b = __float2bfloat16(a1 - __bfloat162float(h1));
            __hip_bfloat16 l2b = __float2bfloat16(a2 - __bfloat162float(h2));
            __hip_bfloat16 l3b = __float2bfloat16(a3 - __bfloat162float(h3));
            ushort4 hv = make_ushort4(*(unsigned short*)&h0, *(unsigned short*)&h1,
                                      *(unsigned short*)&h2, *(unsigned short*)&h3);
            ushort4 lv = make_ushort4(*(unsigned short*)&l0b, *(unsigned short*)&l1b,
                                      *(unsigned short*)&l2b, *(unsigned short*)&l3b);
            unsigned short* yrow = y2 + row * 2 * DINNER + d0 + g4;
            *(ushort4*)&yrow[0] = hv;
            *(ushort4*)&yrow[DINNER] = lv;
        }
    }

    if (!PASS3) {
        *(float4*)&Pbuf[psoff] = make_float4(expf(Ac[0] * sdl), expf(Ac[1] * sdl),
                                             expf(Ac[2] * sdl), expf(Ac[3] * sdl));
        *(float4*)&Sbuf[psoff] = make_float4(h[0], h[1], h[2], h[3]);
    }
}

__global__ __launch_bounds__(256) void scan_combine(
    const float* __restrict__ Pbuf, float* __restrict__ Sbuf)
{
    int t = blockIdx.x * 256 + threadIdx.x;
    int b = t >> 15;
    int rem = t & 32767;
    size_t base = (size_t)b * CH * DINNER * DSTATE + rem;
    float H = 0.f;
#pragma unroll 4
    for (int c = 0; c < CH; ++c) {
        size_t off = base + (size_t)c * DINNER * DSTATE;
        float S = Sbuf[off];
        float P = Pbuf[off];
        Sbuf[off] = H;
        H = fmaf(P, H, S);
    }
}

// ---------------------------------------------------------------------------
extern "C" void kernel_launch(void* const* d_in, const int* in_sizes, int n_in,
                              void* d_out, int out_size, void* d_ws, size_t ws_size,
                              hipStream_t stream)
{
    const float* x          = (const float*)d_in[0];
    const float* in_proj_w  = (const float*)d_in[1];
    const float* conv_w     = (const float*)d_in[2];
    const float* conv_b     = (const float*)d_in[3];
    const float* x_proj_w   = (const float*)d_in[4];
    const float* dt_proj_w  = (const float*)d_in[5];
    const float* dt_proj_b  = (const float*)d_in[6];
    const float* A_log      = (const float*)d_in[7];
    const float* Dv         = (const float*)d_in[8];
    const float* out_proj_w = (const float*)d_in[9];
    float* out = (float*)d_out;

    // workspace layout (bytes):
    char* w = (char*)d_ws;
    float* xz   = (float*)(w);                       // 64 MB
    float* u    = (float*)(w + 67108864);            // 32 MB (written step 3)
    float* dbuf = (float*)(w + 100663296);           // 32 MB (written step 5)
    float* xdbl = (float*)(w + 134217728);           // 1.5 MB
    float* Pbuf = (float*)(w + 135790592);           // 8 MB
    float* Sbuf = (float*)(w + 144179200);           // 8 MB (ends 152567808)
    unsigned short* y2  = (unsigned short*)(w + 152567808);   // 32 MB (stage 6+)
    unsigned short* w2b = (unsigned short*)(w + 135790592);   // 8 MB over Pbuf (dead at 7)
    float* Cp = (float*)(w + 152567808);             // xproj partials (dead at 4, pre-y2)
    // panelized 3-seg bf16 inputs for in_proj; ALIAS u / dbuf (dead after step 2)
    unsigned short* x2p  = (unsigned short*)(w + 67108864);   // 24 MB over u
    unsigned short* w2ap = (unsigned short*)(w + 100663296);  // 24 MB over dbuf

    // 1) split x / in_proj_w to 3-segment panelized bf16 (K' = 3072, LDS-image order)
    split3_kernel<1><<<2048, 256, 0, stream>>>(x, x2p);          // [h,l,h]
    split3_kernel<2><<<2048, 256, 0, stream>>>(in_proj_w, w2ap); // [h,h,l]
    // 2) in_proj via 8-phase 256^2 pipelined MFMA GEMM (KT=48)
    gemm_8ph<48><<<256, 512, 0, stream>>>(x2p, w2ap, xz, 4096);
    // 3) conv + silu -> u (overwrites x2p, dead)
    conv_silu_v4<<<(M_ROWS * 512) / 256, 256, 0, stream>>>(xz, conv_w, conv_b, u);
    // 4) x_proj via split-K
    {
        dim3 g(KSPLIT, M_ROWS / 64);
        xproj_splitk<<<g, 256, 0, stream>>>(u, x_proj_w, Cp);
        xproj_reduce<<<(M_ROWS * 96) / 256, 256, 0, stream>>>(Cp, xdbl);
    }
    // 5) dt_proj + softplus -> dbuf (K=64 staged once; overwrites w2ap, dead)
    {
        dim3 g(DINNER / 128, M_ROWS / 64);
        dtproj_kernel<<<g, 256, 0, stream>>>(xdbl, dt_proj_w, dt_proj_b, dbuf);
    }
    // 6) chunked selective scan; pass3 fuses gate + split into y2
    {
        const int nblk = B_SZ * (DINNER / CPB) * CH;
        scan_chunk<false><<<nblk, 256, 0, stream>>>(dbuf, u, xdbl, A_log, Dv, Pbuf, Sbuf, nullptr, nullptr);
        scan_combine<<<B_SZ * DINNER * DSTATE / 256, 256, 0, stream>>>(Pbuf, Sbuf);
        scan_chunk<true><<<nblk, 256, 0, stream>>>(dbuf, u, xdbl, A_log, Dv, nullptr, Sbuf, xz, y2);
    }
    // 7) split out_proj_w (2-seg, old path)
    split2_kernel<<<(DMODEL * DINNER) / 256, 256, 0, stream>>>(out_proj_w, w2b, DINNER);
    // 8) out_proj via 32x32x16 MFMA (R8 structure, control)
    {
        dim3 g(1024 / 64, M_ROWS / 128);
        gemm_bf16_nt<64, 2048><<<g, 256, 0, stream>>>(y2, w2b, out, 1024);
    }
}

// Round 5
// 496.196 us; speedup vs baseline: 1.2371x; 1.0093x over previous
//
#include <hip/hip_runtime.h>
#include <hip/hip_bf16.h>
#include <math.h>

#define B_SZ 2
#define L_SZ 2048
#define DMODEL 1024
#define DINNER 2048
#define DSTATE 16
#define DTRANK 64
#define M_ROWS (B_SZ * L_SZ)   // 4096

#define CH 32
#define CLEN (L_SZ / CH)
#define CPB 64

#define KSPLIT 8
#define KC (DINNER / KSPLIT)   // 256

typedef short shortx8 __attribute__((ext_vector_type(8)));
typedef float floatx4 __attribute__((ext_vector_type(4)));
typedef float floatx16 __attribute__((ext_vector_type(16)));

__device__ __forceinline__ float softplusf(float x) {
    return fmaxf(x, 0.f) + log1pf(expf(-fabsf(x)));
}
__device__ __forceinline__ float siluf(float x) {
    return x * (1.f / (1.f + expf(-x)));
}

__device__ __forceinline__ void async_ld16(const void* g, void* l) {
    __builtin_amdgcn_global_load_lds(
        (__attribute__((address_space(1))) void*)(unsigned long long)g,
        (__attribute__((address_space(3))) void*)(unsigned int)(unsigned long long)l,
        16, 0, 0);
}

// ---------------------------------------------------------------------------
// R14: ONLY change vs R13 = gemm_8ph vmcnt schedule 4->2 waits per 8 phases
// (m201-faithful: "vmcnt(N) only at phases 4 and 8, never 0 in main loop").
// R13 measured 92us @ MfmaUtil 47% with waits every other phase; per-phase
// budget shows 621cyc MFMA floor vs 1150cyc elapsed -- the extra CU-wide
// sync points (1 block/CU, nothing fills the SIMD during a stall) are the
// prime suspect for the 15-point gap to m201's 62%.
// New accounting (verified by queue trace): prologue drains t0 fully via
// vmcnt(4) (leaves t1.A0/B0 in flight); steady state stages 1 region/phase
// in order [t+1.A1, t+1.B1, t+2.A0, t+2.B0 | t+2.A1, t+2.B1, t+3.A0,
// t+3.B0]; vmcnt(4) at phases 4 and 8 drains the 8 oldest loads = exactly
// the 4 regions the next 4 phases read, issued 4-7 phases earlier (HBM
// latency fully covered). Barrier-after-wait preserves cross-wave LDS
// visibility; stage-target safety is barrier-based and unchanged.
// ---------------------------------------------------------------------------

// fp32 -> 3-segment panelized bf16 in LDS-image order.
// LO==1 (A/activations): segs [h, l, h];  LO==2 (B/weights): segs [h, h, l]
// => sum over K' = xh*wh + xl*wh + xh*wl  (same split-fp32 triple as R8).
template <int LO>
__global__ __launch_bounds__(256) void split3_kernel(
    const float* __restrict__ src, unsigned short* __restrict__ dst)
{
    int i = blockIdx.x * 256 + threadIdx.x;   // 4096 rows x 128 k8-groups
    int row = i & 4095;
    int k8s = i >> 12;                        // 0..127
    const float* s = src + (size_t)row * 1024 + k8s * 8;
    float4 v0 = *(const float4*)s;
    float4 v1 = *(const float4*)(s + 4);
    float vs[8] = {v0.x, v0.y, v0.z, v0.w, v1.x, v1.y, v1.z, v1.w};
    unsigned short hsv[8], lsv[8];
#pragma unroll
    for (int j = 0; j < 8; ++j) {
        __hip_bfloat16 h = __float2bfloat16(vs[j]);
        __hip_bfloat16 l = __float2bfloat16(vs[j] - __bfloat162float(h));
        hsv[j] = *(unsigned short*)&h;
        lsv[j] = *(unsigned short*)&l;
    }
    shortx8 hv = *(shortx8*)hsv;
    shortx8 lv = *(shortx8*)lsv;
    int p = row >> 8, rr = row & 255;
    int tloc = k8s >> 3;
    int sh = (k8s >> 2) & 1;
    int k8l = k8s & 3;
    size_t unit = (size_t)(k8l * 256 + rr) * 8;
#pragma unroll
    for (int e = 0; e < 3; ++e) {
        int T = e * 16 + tloc;
        size_t off = (size_t)(p * 96 + T * 2 + sh) * 8192 + unit;
        shortx8 val = (LO == 1) ? (e == 1 ? lv : hv) : (e == 2 ? lv : hv);
        *(shortx8*)&dst[off] = val;
    }
}

// ---------------------------------------------------------------------------
// 8-phase 256x256 pipelined bf16 GEMM. KT = K'/64 tiles (must be even).
// Grid = (M/256)*(N/256) = 256 blocks, 512 threads.
// ---------------------------------------------------------------------------
template <int KT>
__global__ __launch_bounds__(512, 2) void gemm_8ph(
    const unsigned short* __restrict__ Ap,
    const unsigned short* __restrict__ Bp,
    float* __restrict__ C, int ldc)
{
    __shared__ unsigned short lds[65536];   // 128KB: [slot][A|B][kh][k8l*256+row]*8

    const int tid = threadIdx.x;
    const int lane = tid & 63;
    const int w = tid >> 6;                 // 0..7
    const int wm = w >> 2, wn = w & 3;      // 2 x 4
    const int l15 = lane & 15, l4 = lane >> 4;

    int id = blockIdx.x;
    id = (id & 7) * 32 + (id >> 3);         // bijective XCD swizzle (256 blocks)
    const int bm = id >> 4, bn = id & 15;

    const unsigned short* ga = Ap + (size_t)bm * KT * 16384;
    const unsigned short* gb = Bp + (size_t)bn * KT * 16384;

    const int rA = (l4 * 256 + wm * 128 + l15) * 8;   // + frag*128 + s*8192 + slot
    const int rB = (l4 * 256 + wn * 64 + l15) * 8;    // + frag*128 + 16384 + ...

    floatx4 acc[8][4] = {};
    shortx8 bfr[4];

    // stage one 16KB region: slot=(vt&1), ab in {0=A,1=B}, s = k-half
    auto STAGE = [&](int vt, int ab, int s) {
        int T = vt < KT ? vt : KT - 1;     // virtual tiles clamp source (counts stay exact)
        const unsigned short* src = (ab ? gb : ga) + ((size_t)T * 2 + s) * 8192 + tid * 8;
        unsigned short* dst = (unsigned short*)lds + (vt & 1) * 32768 + ab * 16384 + s * 8192 + tid * 8;
        async_ld16(src, dst);
        async_ld16(src + 4096, dst + 4096);
    };

#define MFMA16(MH)                                                                             \
    acc[(MH)*4+0][0] = __builtin_amdgcn_mfma_f32_16x16x32_bf16(af0, bfr[0], acc[(MH)*4+0][0], 0,0,0); \
    acc[(MH)*4+0][1] = __builtin_amdgcn_mfma_f32_16x16x32_bf16(af0, bfr[1], acc[(MH)*4+0][1], 0,0,0); \
    acc[(MH)*4+0][2] = __builtin_amdgcn_mfma_f32_16x16x32_bf16(af0, bfr[2], acc[(MH)*4+0][2], 0,0,0); \
    acc[(MH)*4+0][3] = __builtin_amdgcn_mfma_f32_16x16x32_bf16(af0, bfr[3], acc[(MH)*4+0][3], 0,0,0); \
    acc[(MH)*4+1][0] = __builtin_amdgcn_mfma_f32_16x16x32_bf16(af1, bfr[0], acc[(MH)*4+1][0], 0,0,0); \
    acc[(MH)*4+1][1] = __builtin_amdgcn_mfma_f32_16x16x32_bf16(af1, bfr[1], acc[(MH)*4+1][1], 0,0,0); \
    acc[(MH)*4+1][2] = __builtin_amdgcn_mfma_f32_16x16x32_bf16(af1, bfr[2], acc[(MH)*4+1][2], 0,0,0); \
    acc[(MH)*4+1][3] = __builtin_amdgcn_mfma_f32_16x16x32_bf16(af1, bfr[3], acc[(MH)*4+1][3], 0,0,0); \
    acc[(MH)*4+2][0] = __builtin_amdgcn_mfma_f32_16x16x32_bf16(af2, bfr[0], acc[(MH)*4+2][0], 0,0,0); \
    acc[(MH)*4+2][1] = __builtin_amdgcn_mfma_f32_16x16x32_bf16(af2, bfr[1], acc[(MH)*4+2][1], 0,0,0); \
    acc[(MH)*4+2][2] = __builtin_amdgcn_mfma_f32_16x16x32_bf16(af2, bfr[2], acc[(MH)*4+2][2], 0,0,0); \
    acc[(MH)*4+2][3] = __builtin_amdgcn_mfma_f32_16x16x32_bf16(af2, bfr[3], acc[(MH)*4+2][3], 0,0,0); \
    acc[(MH)*4+3][0] = __builtin_amdgcn_mfma_f32_16x16x32_bf16(af3, bfr[0], acc[(MH)*4+3][0], 0,0,0); \
    acc[(MH)*4+3][1] = __builtin_amdgcn_mfma_f32_16x16x32_bf16(af3, bfr[1], acc[(MH)*4+3][1], 0,0,0); \
    acc[(MH)*4+3][2] = __builtin_amdgcn_mfma_f32_16x16x32_bf16(af3, bfr[2], acc[(MH)*4+3][2], 0,0,0); \
    acc[(MH)*4+3][3] = __builtin_amdgcn_mfma_f32_16x16x32_bf16(af3, bfr[3], acc[(MH)*4+3][3], 0,0,0);

// VM: 0 = no wait; 1 = counted s_waitcnt vmcnt(4) (phases 4 and 8 only)
#define PHASE(SLOT, S, MH, SVT, SAB, SS, VM)                                   \
    {                                                                          \
        const unsigned short* Ab = &lds[(SLOT)*32768 + (S)*8192] + rA;         \
        shortx8 af0 = *(const shortx8*)&Ab[((MH)*4 + 0) * 128];                \
        shortx8 af1 = *(const shortx8*)&Ab[((MH)*4 + 1) * 128];                \
        shortx8 af2 = *(const shortx8*)&Ab[((MH)*4 + 2) * 128];                \
        shortx8 af3 = *(const shortx8*)&Ab[((MH)*4 + 3) * 128];                \
        if ((MH) == 0) {                                                       \
            const unsigned short* Bb = &lds[(SLOT)*32768 + 16384 + (S)*8192] + rB; \
            bfr[0] = *(const shortx8*)&Bb[0];                                  \
            bfr[1] = *(const shortx8*)&Bb[128];                                \
            bfr[2] = *(const shortx8*)&Bb[256];                                \
            bfr[3] = *(const shortx8*)&Bb[384];                                \
        }                                                                      \
        STAGE(SVT, SAB, SS);                                                   \
        __builtin_amdgcn_s_barrier();                                          \
        asm volatile("s_waitcnt lgkmcnt(0)" ::: "memory");                     \
        __builtin_amdgcn_s_setprio(1);                                         \
        MFMA16(MH)                                                             \
        __builtin_amdgcn_s_setprio(0);                                         \
        if (VM) { asm volatile("s_waitcnt vmcnt(4)" ::: "memory"); }           \
        __builtin_amdgcn_s_barrier();                                          \
    }

    // prologue: t0 all 4 regions + t1 first 2, in consumption order.
    // vmcnt(4) drains ALL of t0 (phases 1-4 read it); leaves t1.A0/B0 in flight.
    STAGE(0, 0, 0); STAGE(0, 1, 0); STAGE(0, 0, 1); STAGE(0, 1, 1);
    STAGE(1, 0, 0); STAGE(1, 1, 0);
    asm volatile("s_waitcnt vmcnt(4)" ::: "memory");
    __builtin_amdgcn_s_barrier();

#pragma unroll 1
    for (int i = 0; i < KT / 2; ++i) {
        const int t2 = 2 * i;
        PHASE(0, 0, 0, t2 + 1, 0, 1, 0)   // read t(2i) s0 mh0 ; stage (2i+1).A-kh1
        PHASE(0, 0, 1, t2 + 1, 1, 1, 0)   //                    stage (2i+1).B-kh1
        PHASE(0, 1, 0, t2 + 2, 0, 0, 0)   // read t(2i) s1     ; stage (2i+2).A-kh0
        PHASE(0, 1, 1, t2 + 2, 1, 0, 1)   //  vmcnt(4): drains all 4 regions of t(2i+1)
        PHASE(1, 0, 0, t2 + 2, 0, 1, 0)   // read t(2i+1) s0   ; stage (2i+2).A-kh1
        PHASE(1, 0, 1, t2 + 2, 1, 1, 0)   //                    stage (2i+2).B-kh1
        PHASE(1, 1, 0, t2 + 3, 0, 0, 0)   // read t(2i+1) s1   ; stage (2i+3).A-kh0
        PHASE(1, 1, 1, t2 + 3, 1, 0, 1)   //  vmcnt(4): drains all 4 regions of t(2i+2)
    }

#undef PHASE
#undef MFMA16

    // epilogue: C/D 16x16: col = lane&15, row = (lane>>4)*4 + reg (m89)
    const int c0 = bn * 256 + wn * 64;
    const int r0 = bm * 256 + wm * 128;
#pragma unroll
    for (int fi = 0; fi < 8; ++fi) {
#pragma unroll
        for (int fj = 0; fj < 4; ++fj) {
            int col = c0 + fj * 16 + l15;
            int rowb = r0 + fi * 16 + l4 * 4;
#pragma unroll
            for (int ri = 0; ri < 4; ++ri)
                C[(size_t)(rowb + ri) * ldc + col] = acc[fi][fj][ri];
        }
    }
}

// ---------------------------------------------------------------------------
// bf16 MFMA GEMM (R8 structure) -- out_proj (control).
// ---------------------------------------------------------------------------
template <int BN, int KP>
__global__ __launch_bounds__(256) void gemm_bf16_nt(
    const unsigned short* __restrict__ A,
    const unsigned short* __restrict__ Bm,
    float* __restrict__ C, int ldc)
{
    constexpr int TN32 = BN / 64;                 // 32-wide n-tiles per wave
    __shared__ unsigned short As[2 * 8192];       // [seg][t][128 rows][32 k]
    __shared__ unsigned short Bs[2 * BN * 64];    // [seg][t][BN rows][32 k]

    const int tid = threadIdx.x;
    const int w = tid >> 6;
    const int lane = tid & 63;
    const int wm = w >> 1, wn = w & 1;
    const int m0 = blockIdx.y * 128;
    const int n0 = blockIdx.x * BN;

    const int r4 = lane >> 2;                        // staging row in 16-group
    const int csw = (lane & 3) ^ ((r4 >> 1) & 3);    // swizzled source chunk
    const int gk = csw * 8;                          // shorts offset
    const int l31 = lane & 31;
    const int khalf = lane >> 5;                     // 0/1: k-half within 16
    const int rsw = (l31 >> 1) & 3;                  // read-side swizzle key

    floatx16 acc[2][TN32] = {};

    for (int k0 = 0; k0 < KP; k0 += 64) {
#pragma unroll
        for (int seg = 0; seg < 2; ++seg) {
            const unsigned short* Asrc = A + seg * KP;
            const unsigned short* Bsrc = Bm + seg * KP;
#pragma unroll
            for (int t = 0; t < 2; ++t) {
#pragma unroll
                for (int jj = 0; jj < 2; ++jj) {
                    int j = w + jj * 4;
                    async_ld16(Asrc + (size_t)(m0 + j * 16 + r4) * (2 * KP) + k0 + t * 32 + gk,
                               &As[seg * 8192 + t * 4096 + j * 512]);
                }
#pragma unroll
                for (int jj = 0; jj < BN / 64; ++jj) {
                    int j = w + jj * 4;
                    async_ld16(Bsrc + (size_t)(n0 + j * 16 + r4) * (2 * KP) + k0 + t * 32 + gk,
                               &Bs[seg * BN * 64 + t * BN * 32 + j * 512]);
                }
            }
        }
        __syncthreads();

#pragma unroll
        for (int t = 0; t < 2; ++t) {
#pragma unroll
            for (int kk = 0; kk < 2; ++kk) {
                const int pos = ((kk * 2 + khalf) ^ rsw) << 3;
                shortx8 ah[2], al[2], bh[TN32], bl[TN32];
#pragma unroll
                for (int i = 0; i < 2; ++i) {
                    int row = wm * 64 + i * 32 + l31;
                    ah[i] = *(const shortx8*)&As[t * 4096 + row * 32 + pos];
                    al[i] = *(const shortx8*)&As[8192 + t * 4096 + row * 32 + pos];
                }
#pragma unroll
                for (int j = 0; j < TN32; ++j) {
                    int col = wn * (BN / 2) + j * 32 + l31;
                    bh[j] = *(const shortx8*)&Bs[t * BN * 32 + col * 32 + pos];
                    bl[j] = *(const shortx8*)&Bs[BN * 64 + t * BN * 32 + col * 32 + pos];
                }
#pragma unroll
                for (int i = 0; i < 2; ++i)
#pragma unroll
                    for (int j = 0; j < TN32; ++j) {
                        acc[i][j] = __builtin_amdgcn_mfma_f32_32x32x16_bf16(ah[i], bh[j], acc[i][j], 0, 0, 0);
                        acc[i][j] = __builtin_amdgcn_mfma_f32_32x32x16_bf16(ah[i], bl[j], acc[i][j], 0, 0, 0);
                        acc[i][j] = __builtin_amdgcn_mfma_f32_32x32x16_bf16(al[i], bh[j], acc[i][j], 0, 0, 0);
                    }
            }
        }
        __syncthreads();
    }

#pragma unroll
    for (int i = 0; i < 2; ++i) {
#pragma unroll
        for (int j = 0; j < TN32; ++j) {
            int col = n0 + wn * (BN / 2) + j * 32 + l31;
#pragma unroll
            for (int r = 0; r < 16; ++r) {
                int row = m0 + wm * 64 + i * 32 + (r & 3) + 8 * (r >> 2) + 4 * khalf;
                C[(size_t)row * ldc + col] = acc[i][j][r];
            }
        }
    }
}

// ---------------------------------------------------------------------------
// fp32 -> 2-segment split-bf16: row = [hi (K) | lo (K)], stride 2K (out_proj)
// ---------------------------------------------------------------------------
__global__ __launch_bounds__(256) void split2_kernel(
    const float* __restrict__ src, unsigned short* __restrict__ dst, int K)
{
    int i = blockIdx.x * 256 + threadIdx.x;
    int m = i / K;
    int k = i - m * K;
    float a = src[i];
    __hip_bfloat16 h = __float2bfloat16(a);
    __hip_bfloat16 l = __float2bfloat16(a - __bfloat162float(h));
    unsigned short* row = dst + (size_t)m * 2 * K;
    row[k] = *(unsigned short*)&h;
    row[K + k] = *(unsigned short*)&l;
}

// ---------------------------------------------------------------------------
// x_proj split-K partial GEMM + reduce
// ---------------------------------------------------------------------------
__global__ __launch_bounds__(256) void xproj_splitk(
    const float* __restrict__ u, const float* __restrict__ Wx,
    float* __restrict__ Cp)
{
    __shared__ float As[16][68];
    __shared__ float Bs[16][100];

    const int tid = threadIdx.x;
    const int ks = blockIdx.x;
    const int m0 = blockIdx.y * 64;
    const int tx = tid & 15;
    const int ty = tid >> 4;

    float acc[4][6] = {};

    const int arow = tid >> 2;
    const int akk = (tid & 3) * 4;

    for (int k0 = ks * KC; k0 < (ks + 1) * KC; k0 += 16) {
        {
            float4 v = *(const float4*)&u[(size_t)(m0 + arow) * DINNER + k0 + akk];
            As[akk + 0][arow] = v.x;
            As[akk + 1][arow] = v.y;
            As[akk + 2][arow] = v.z;
            As[akk + 3][arow] = v.w;
        }
        for (int idx = tid; idx < 384; idx += 256) {
            int row = idx >> 2;
            int kk = (idx & 3) * 4;
            float4 v = *(const float4*)&Wx[(size_t)row * DINNER + k0 + kk];
            Bs[kk + 0][row] = v.x;
            Bs[kk + 1][row] = v.y;
            Bs[kk + 2][row] = v.z;
            Bs[kk + 3][row] = v.w;
        }
        __syncthreads();

#pragma unroll
        for (int k = 0; k < 16; ++k) {
            float a[4], b[6];
#pragma unroll
            for (int i = 0; i < 4; ++i) a[i] = As[k][ty * 4 + i];
#pragma unroll
            for (int j = 0; j < 6; ++j) b[j] = Bs[k][tx * 6 + j];
#pragma unroll
            for (int i = 0; i < 4; ++i)
#pragma unroll
                for (int j = 0; j < 6; ++j) acc[i][j] = fmaf(a[i], b[j], acc[i][j]);
        }
        __syncthreads();
    }

    float* outp = Cp + ((size_t)ks * M_ROWS + m0) * 96;
#pragma unroll
    for (int i = 0; i < 4; ++i)
#pragma unroll
        for (int j = 0; j < 6; ++j)
            outp[(ty * 4 + i) * 96 + tx * 6 + j] = acc[i][j];
}

__global__ __launch_bounds__(256) void xproj_reduce(
    const float* __restrict__ Cp, float* __restrict__ xdbl)
{
    int i = blockIdx.x * 256 + threadIdx.x;
    float s = 0.f;
#pragma unroll
    for (int c = 0; c < KSPLIT; ++c)
        s += Cp[(size_t)c * M_ROWS * 96 + i];
    xdbl[i] = s;
}

// ---------------------------------------------------------------------------
// dt_proj + softplus, K=64 staged once. A = xdbl[:, :64] (lda 96),
// B = dt_proj_w [2048][64]. Tile 64(M) x 128(N), 256 thr, TM4 x TN8.
// ---------------------------------------------------------------------------
__global__ __launch_bounds__(256) void dtproj_kernel(
    const float* __restrict__ A, const float* __restrict__ Bw,
    const float* __restrict__ bias, float* __restrict__ Cout)
{
    __shared__ float As[64][68];     // [k][row], float4-aligned rows (272B)
    __shared__ float Bs[64][132];    // [k][row], float4-aligned rows (528B)

    const int tid = threadIdx.x;
    const int m0 = blockIdx.y * 64;
    const int n0 = blockIdx.x * 128;
    const int tx = tid & 15;         // 8 cols each
    const int ty = tid >> 4;         // 4 rows each

    // stage A: 64 rows x 64 k (k-major in LDS)
    for (int idx = tid * 4; idx < 64 * 64; idx += 1024) {
        int row = idx >> 6, kk = idx & 63;
        float4 v = *(const float4*)&A[(size_t)(m0 + row) * 96 + kk];
        As[kk + 0][row] = v.x;
        As[kk + 1][row] = v.y;
        As[kk + 2][row] = v.z;
        As[kk + 3][row] = v.w;
    }
    // stage B: 128 rows x 64 k
    for (int idx = tid * 4; idx < 128 * 64; idx += 1024) {
        int row = idx >> 6, kk = idx & 63;
        float4 v = *(const float4*)&Bw[(size_t)(n0 + row) * 64 + kk];
        Bs[kk + 0][row] = v.x;
        Bs[kk + 1][row] = v.y;
        Bs[kk + 2][row] = v.z;
        Bs[kk + 3][row] = v.w;
    }
    __syncthreads();

    float acc[4][8] = {};
#pragma unroll 8
    for (int k = 0; k < 64; ++k) {
        float a[4], b[8];
        *(float4*)a = *(const float4*)&As[k][ty * 4];
        *(float4*)&b[0] = *(const float4*)&Bs[k][tx * 8];
        *(float4*)&b[4] = *(const float4*)&Bs[k][tx * 8 + 4];
#pragma unroll
        for (int i = 0; i < 4; ++i)
#pragma unroll
            for (int j = 0; j < 8; ++j) acc[i][j] = fmaf(a[i], b[j], acc[i][j]);
    }

#pragma unroll
    for (int i = 0; i < 4; ++i) {
        int m = m0 + ty * 4 + i;
        float o[8];
#pragma unroll
        for (int j = 0; j < 8; ++j)
            o[j] = softplusf(acc[i][j] + bias[n0 + tx * 8 + j]);
        float* dst = &Cout[(size_t)m * DINNER + n0 + tx * 8];
        *(float4*)&dst[0] = *(float4*)&o[0];
        *(float4*)&dst[4] = *(float4*)&o[4];
    }
}

// ---------------------------------------------------------------------------
// conv + silu, float4 over channels
// ---------------------------------------------------------------------------
__global__ __launch_bounds__(256) void conv_silu_v4(
    const float* __restrict__ xz, const float* __restrict__ cw,
    const float* __restrict__ cb, float* __restrict__ u)
{
    int i = blockIdx.x * 256 + threadIdx.x;      // over M_ROWS * 512
    int dq = (i & 511) << 2;
    int bl = i >> 9;
    int b = bl >> 11;
    int l = bl & 2047;

    float4 W0 = *(const float4*)&cw[(dq + 0) * 4];
    float4 W1 = *(const float4*)&cw[(dq + 1) * 4];
    float4 W2 = *(const float4*)&cw[(dq + 2) * 4];
    float4 W3 = *(const float4*)&cw[(dq + 3) * 4];
    float4 acc = *(const float4*)&cb[dq];

#pragma unroll
    for (int k = 0; k < 4; ++k) {
        int ls = l + k - 3;
        if (ls >= 0) {
            float4 v = *(const float4*)&xz[((size_t)(b << 11) + ls) * 4096 + dq];
            acc.x = fmaf(v.x, ((const float*)&W0)[k], acc.x);
            acc.y = fmaf(v.y, ((const float*)&W1)[k], acc.y);
            acc.z = fmaf(v.z, ((const float*)&W2)[k], acc.z);
            acc.w = fmaf(v.w, ((const float*)&W3)[k], acc.w);
        }
    }
    float4 r = make_float4(siluf(acc.x), siluf(acc.y), siluf(acc.z), siluf(acc.w));
    *(float4*)&u[(size_t)bl * DINNER + dq] = r;
}

// ---------------------------------------------------------------------------
// Chunked selective scan (3 passes). PASS3 fuses gate + split-bf16 y2.
// ---------------------------------------------------------------------------
template <bool PASS3>
__global__ __launch_bounds__(256) void scan_chunk(
    const float* __restrict__ dbuf, const float* __restrict__ ubuf,
    const float* __restrict__ xdbl, const float* __restrict__ A_log,
    const float* __restrict__ Dv,
    float* __restrict__ Pbuf, float* __restrict__ Sbuf,
    const float* __restrict__ xz, unsigned short* __restrict__ y2)
{
    __shared__ float sd[16][CPB];
    __shared__ float su[16][CPB];
    __shared__ float sB[16][DSTATE];
    __shared__ float sC[16][DSTATE];

    const int tid = threadIdx.x;
    const int c    = blockIdx.x % CH;
    const int dblk = (blockIdx.x / CH) % (DINNER / CPB);
    const int b    = blockIdx.x / (CH * (DINNER / CPB));
    const int d0 = dblk * CPB;
    const int dg = tid >> 2;
    const int q  = tid & 3;
    const int d  = d0 + dg;
    const size_t base_bl = (size_t)b * L_SZ + (size_t)c * CLEN;

    float Ac[4], h[4];
    float sdl = 0.f;
#pragma unroll
    for (int j = 0; j < 4; ++j)
        Ac[j] = -expf(A_log[d * DSTATE + 4 * q + j]);
    const size_t psoff = (((size_t)b * CH + c) * DINNER + d0) * DSTATE + (size_t)tid * 4;
    if (PASS3) {
        float4 h0 = *(const float4*)&Sbuf[psoff];
        h[0] = h0.x; h[1] = h0.y; h[2] = h0.z; h[3] = h0.w;
    } else {
        h[0] = h[1] = h[2] = h[3] = 0.f;
    }
    const float Dd = PASS3 ? Dv[d] : 0.f;

    const int ls = tid >> 4;
    const int g4 = (tid & 15) * 4;
    const int ln = tid & 15;

    float4 r_d = *(const float4*)&dbuf[(base_bl + ls) * DINNER + d0 + g4];
    float4 r_u = *(const float4*)&ubuf[(base_bl + ls) * DINNER + d0 + g4];
    float r_B = xdbl[(base_bl + ls) * 96 + 64 + ln];
    float r_C = xdbl[(base_bl + ls) * 96 + 80 + ln];

    for (int l0 = 0; l0 < CLEN; l0 += 16) {
        __syncthreads();
        *(float4*)&sd[ls][g4] = r_d;
        *(float4*)&su[ls][g4] = r_u;
        sB[ls][ln] = r_B;
        sC[ls][ln] = r_C;
        __syncthreads();

        if (l0 + 16 < CLEN) {
            r_d = *(const float4*)&dbuf[(base_bl + l0 + 16 + ls) * DINNER + d0 + g4];
            r_u = *(const float4*)&ubuf[(base_bl + l0 + 16 + ls) * DINNER + d0 + g4];
            r_B = xdbl[(base_bl + l0 + 16 + ls) * 96 + 64 + ln];
            r_C = xdbl[(base_bl + l0 + 16 + ls) * 96 + 80 + ln];
        }

#pragma unroll
        for (int s = 0; s < 16; ++s) {
            float dl = sd[s][dg];
            float ul = su[s][dg];
            float4 Bv = *(float4*)&sB[s][4 * q];
            float dbu = dl * ul;
            float dA0 = expf(dl * Ac[0]);
            float dA1 = expf(dl * Ac[1]);
            float dA2 = expf(dl * Ac[2]);
            float dA3 = expf(dl * Ac[3]);
            h[0] = fmaf(dA0, h[0], dbu * Bv.x);
            h[1] = fmaf(dA1, h[1], dbu * Bv.y);
            h[2] = fmaf(dA2, h[2], dbu * Bv.z);
            h[3] = fmaf(dA3, h[3], dbu * Bv.w);
            if (!PASS3) {
                sdl += dl;
            } else {
                float4 Cv = *(float4*)&sC[s][4 * q];
                float y = h[0] * Cv.x + h[1] * Cv.y + h[2] * Cv.z + h[3] * Cv.w;
                y += __shfl_xor(y, 1);
                y += __shfl_xor(y, 2);
                if (q == 0) su[s][dg] = fmaf(ul, Dd, y);
            }
        }

        if (PASS3) {
            __syncthreads();
            size_t row = base_bl + l0 + ls;
            float4 yv = *(float4*)&su[ls][g4];
            float4 rv = *(const float4*)&xz[row * 4096 + 2048 + d0 + g4];
            float a0 = yv.x * siluf(rv.x);
            float a1 = yv.y * siluf(rv.y);
            float a2 = yv.z * siluf(rv.z);
            float a3 = yv.w * siluf(rv.w);
            __hip_bfloat16 h0 = __float2bfloat16(a0), h1 = __float2bfloat16(a1);
            __hip_bfloat16 h2 = __float2bfloat16(a2), h3 = __float2bfloat16(a3);
            __hip_bfloat16 l0b = __float2bfloat16(a0 - __bfloat162float(h0));
            __hip_bfloat16 l1b = __float2bfloat16(a1 - __bfloat162float(h1));
            __hip_bfloat16 l2b = __float2bfloat16(a2 - __bfloat162float(h2));
            __hip_bfloat16 l3b = __float2bfloat16(a3 - __bfloat162float(h3));
            ushort4 hv = make_ushort4(*(unsigned short*)&h0, *(unsigned short*)&h1,
                                      *(unsigned short*)&h2, *(unsigned short*)&h3);
            ushort4 lv = make_ushort4(*(unsigned short*)&l0b, *(unsigned short*)&l1b,
                                      *(unsigned short*)&l2b, *(unsigned short*)&l3b);
            unsigned short* yrow = y2 + row * 2 * DINNER + d0 + g4;
            *(ushort4*)&yrow[0] = hv;
            *(ushort4*)&yrow[DINNER] = lv;
        }
    }

    if (!PASS3) {
        *(float4*)&Pbuf[psoff] = make_float4(expf(Ac[0] * sdl), expf(Ac[1] * sdl),
                                             expf(Ac[2] * sdl), expf(Ac[3] * sdl));
        *(float4*)&Sbuf[psoff] = make_float4(h[0], h[1], h[2], h[3]);
    }
}

__global__ __launch_bounds__(256) void scan_combine(
    const float* __restrict__ Pbuf, float* __restrict__ Sbuf)
{
    int t = blockIdx.x * 256 + threadIdx.x;
    int b = t >> 15;
    int rem = t & 32767;
    size_t base = (size_t)b * CH * DINNER * DSTATE + rem;
    float H = 0.f;
#pragma unroll 4
    for (int c = 0; c < CH; ++c) {
        size_t off = base + (size_t)c * DINNER * DSTATE;
        float S = Sbuf[off];
        float P = Pbuf[off];
        Sbuf[off] = H;
        H = fmaf(P, H, S);
    }
}

// ---------------------------------------------------------------------------
extern "C" void kernel_launch(void* const* d_in, const int* in_sizes, int n_in,
                              void* d_out, int out_size, void* d_ws, size_t ws_size,
                              hipStream_t stream)
{
    const float* x          = (const float*)d_in[0];
    const float* in_proj_w  = (const float*)d_in[1];
    const float* conv_w     = (const float*)d_in[2];
    const float* conv_b     = (const float*)d_in[3];
    const float* x_proj_w   = (const float*)d_in[4];
    const float* dt_proj_w  = (const float*)d_in[5];
    const float* dt_proj_b  = (const float*)d_in[6];
    const float* A_log      = (const float*)d_in[7];
    const float* Dv         = (const float*)d_in[8];
    const float* out_proj_w = (const float*)d_in[9];
    float* out = (float*)d_out;

    // workspace layout (bytes):
    char* w = (char*)d_ws;
    float* xz   = (float*)(w);                       // 64 MB
    float* u    = (float*)(w + 67108864);            // 32 MB (written step 3)
    float* dbuf = (float*)(w + 100663296);           // 32 MB (written step 5)
    float* xdbl = (float*)(w + 134217728);           // 1.5 MB
    float* Pbuf = (float*)(w + 135790592);           // 8 MB
    float* Sbuf = (float*)(w + 144179200);           // 8 MB (ends 152567808)
    unsigned short* y2  = (unsigned short*)(w + 152567808);   // 32 MB (stage 6+)
    unsigned short* w2b = (unsigned short*)(w + 135790592);   // 8 MB over Pbuf (dead at 7)
    float* Cp = (float*)(w + 152567808);             // xproj partials (dead at 4, pre-y2)
    // panelized 3-seg bf16 inputs for in_proj; ALIAS u / dbuf (dead after step 2)
    unsigned short* x2p  = (unsigned short*)(w + 67108864);   // 24 MB over u
    unsigned short* w2ap = (unsigned short*)(w + 100663296);  // 24 MB over dbuf

    // 1) split x / in_proj_w to 3-segment panelized bf16 (K' = 3072, LDS-image order)
    split3_kernel<1><<<2048, 256, 0, stream>>>(x, x2p);          // [h,l,h]
    split3_kernel<2><<<2048, 256, 0, stream>>>(in_proj_w, w2ap); // [h,h,l]
    // 2) in_proj via 8-phase 256^2 pipelined MFMA GEMM (KT=48)
    gemm_8ph<48><<<256, 512, 0, stream>>>(x2p, w2ap, xz, 4096);
    // 3) conv + silu -> u (overwrites x2p, dead)
    conv_silu_v4<<<(M_ROWS * 512) / 256, 256, 0, stream>>>(xz, conv_w, conv_b, u);
    // 4) x_proj via split-K
    {
        dim3 g(KSPLIT, M_ROWS / 64);
        xproj_splitk<<<g, 256, 0, stream>>>(u, x_proj_w, Cp);
        xproj_reduce<<<(M_ROWS * 96) / 256, 256, 0, stream>>>(Cp, xdbl);
    }
    // 5) dt_proj + softplus -> dbuf (K=64 staged once; overwrites w2ap, dead)
    {
        dim3 g(DINNER / 128, M_ROWS / 64);
        dtproj_kernel<<<g, 256, 0, stream>>>(xdbl, dt_proj_w, dt_proj_b, dbuf);
    }
    // 6) chunked selective scan; pass3 fuses gate + split into y2
    {
        const int nblk = B_SZ * (DINNER / CPB) * CH;
        scan_chunk<false><<<nblk, 256, 0, stream>>>(dbuf, u, xdbl, A_log, Dv, Pbuf, Sbuf, nullptr, nullptr);
        scan_combine<<<B_SZ * DINNER * DSTATE / 256, 256, 0, stream>>>(Pbuf, Sbuf);
        scan_chunk<true><<<nblk, 256, 0, stream>>>(dbuf, u, xdbl, A_log, Dv, nullptr, Sbuf, xz, y2);
    }
    // 7) split out_proj_w (2-seg, old path)
    split2_kernel<<<(DMODEL * DINNER) / 256, 256, 0, stream>>>(out_proj_w, w2b, DINNER);
    // 8) out_proj via 32x32x16 MFMA (R8 structure, control)
    {
        dim3 g(1024 / 64, M_ROWS / 128);
        gemm_bf16_nt<64, 2048><<<g, 256, 0, stream>>>(y2, w2b, out, 1024);
    }
}